// Round 6
// baseline (521.301 us; speedup 1.0000x reference)
//
#include <hip/hip_runtime.h>
#include <hip/hip_bf16.h>
#include <math.h>

constexpr int NN  = 51200;   // total nodes
constexpr int EE  = 409600;  // edges (without self loops)
constexpr int BB  = 64;      // graphs
constexpr int APG = 64;      // actions per graph
constexpr int NPG = 800;     // nodes per graph
constexpr int SCAN_N = 2 * NN;
constexpr int NA = BB * APG; // 4096 actions
constexpr int KF = 1056;     // padded MLP input dim (1025 -> 33*32)

typedef __bf16 bf16x8 __attribute__((ext_vector_type(8)));
typedef float f32x4 __attribute__((ext_vector_type(4)));
typedef float f32x2 __attribute__((ext_vector_type(2)));
typedef __attribute__((address_space(1))) const void g_void;
typedef __attribute__((address_space(3))) void l_void;

__device__ __forceinline__ float leaky(float x) { return fmaxf(x, 0.2f * x); }
__device__ __forceinline__ float bflo(unsigned w) { return __uint_as_float(w << 16); }
__device__ __forceinline__ float bfhi(unsigned w) { return __uint_as_float(w & 0xffff0000u); }
__device__ __forceinline__ unsigned short f2b(float x) {
  __hip_bfloat16 h = __float2bfloat16(x);
  unsigned short u;
  __builtin_memcpy(&u, &h, 2);
  return u;
}
__device__ __forceinline__ unsigned pack2(float a, float b) {
  return (unsigned)f2b(a) | ((unsigned)f2b(b) << 16);
}

// ---------------- CSR build ----------------
__global__ void count_kernel(const int* __restrict__ ei, int* cnt) {
  int e = blockIdx.x * blockDim.x + threadIdx.x;
  if (e >= EE) return;
  int s = ei[e], d = ei[EE + e];
  atomicAdd(&cnt[d], 1);
  atomicAdd(&cnt[NN + s], 1);
}

__global__ __launch_bounds__(256) void scan1_kernel(const int* __restrict__ cnt,
                                                    int* __restrict__ rp,
                                                    int* __restrict__ bsum) {
  __shared__ int wsum[4];
  int b = blockIdx.x, t = threadIdx.x;
  int base = b * 1024 + t * 4;
  int4 v = *(const int4*)(cnt + base);
  int s = v.x + v.y + v.z + v.w;
  int lane = t & 63, wv = t >> 6;
  int incl = s;
  for (int off = 1; off < 64; off <<= 1) {
    int u = __shfl_up(incl, off);
    if (lane >= off) incl += u;
  }
  if (lane == 63) wsum[wv] = incl;
  __syncthreads();
  int woff = 0;
  for (int i = 0; i < wv; i++) woff += wsum[i];
  int excl = woff + incl - s;
  rp[base] = excl;
  rp[base + 1] = excl + v.x;
  rp[base + 2] = excl + v.x + v.y;
  rp[base + 3] = excl + v.x + v.y + v.z;
  if (t == 255) bsum[b] = woff + incl;
}

__global__ void scan2_kernel(const int* __restrict__ bsum, int* __restrict__ boff,
                             int* __restrict__ rp) {
  __shared__ int w0;
  int t = threadIdx.x;  // 128 threads
  int v = (t < 100) ? bsum[t] : 0;
  int lane = t & 63;
  int incl = v;
  for (int off = 1; off < 64; off <<= 1) {
    int u = __shfl_up(incl, off);
    if (lane >= off) incl += u;
  }
  if (t == 63) w0 = incl;
  __syncthreads();
  int excl = incl - v + ((t >= 64) ? w0 : 0);
  if (t < 100) boff[t] = excl;
  if (t == 99) rp[SCAN_N] = excl + v;
}

__global__ __launch_bounds__(256) void scan3_kernel(int* __restrict__ rp,
                                                    const int* __restrict__ boff) {
  int b = blockIdx.x;
  int off = boff[b];
  int i = b * 1024 + threadIdx.x * 4;
  int4 v = *(int4*)(rp + i);
  v.x += off; v.y += off; v.z += off; v.w += off;
  *(int4*)(rp + i) = v;
}

__global__ void fill_kernel(const int* __restrict__ ei, const int* __restrict__ rp,
                            int* pos, int* __restrict__ col) {
  int e = blockIdx.x * blockDim.x + threadIdx.x;
  if (e >= EE) return;
  int s = ei[e], d = ei[EE + e];
  int p = atomicAdd(&pos[d], 1);
  col[rp[d] + p] = s;
  int q = atomicAdd(&pos[NN + s], 1);
  col[rp[NN + s] + q] = d;
}

// ------- WA precompute: wa[dir*24 + sd*12 + h*3 + c] = W[c]·a[h] over 64 ch -------
__global__ __launch_bounds__(256) void precomp_kernel(const float* __restrict__ Wf,
                                                      const float* __restrict__ Wb,
                                                      const float* __restrict__ asf,
                                                      const float* __restrict__ adf,
                                                      const float* __restrict__ asb,
                                                      const float* __restrict__ adb,
                                                      float* __restrict__ wa) {
  int wave = (blockIdx.x * blockDim.x + threadIdx.x) >> 6;  // 0..47
  int lane = threadIdx.x & 63;
  if (wave >= 48) return;
  int dir = wave / 24, sd = (wave / 12) % 2, h = (wave / 3) % 4, c = wave % 3;
  const float* W = dir ? Wb : Wf;
  const float* a = dir ? (sd ? adb : asb) : (sd ? adf : asf);
  float v = W[c * 256 + h * 64 + lane] * a[h * 64 + lane];
  for (int off = 1; off < 64; off <<= 1) v += __shfl_xor(v, off);
  if (lane == 0) wa[wave] = v;
}

// ------- layer-1 linear + fused al logits (8 ch/thread, both dirs) ----------
// 1600 blocks x 8 iters (R1-isolated win: 12800 trivial blocks = launch floor)
__global__ __launch_bounds__(256) void lin1_kernel(const float* __restrict__ x,
                                                   const float* __restrict__ Wf,
                                                   const float* __restrict__ Wb,
                                                   const float* __restrict__ wa,
                                                   __hip_bfloat16* __restrict__ out,
                                                   float* __restrict__ al_s,
                                                   float* __restrict__ al_d) {
#pragma unroll 1
  for (int itq = 0; itq < 8; ++itq) {
    int idx = blockIdx.x * 2048 + itq * 256 + threadIdx.x;  // SCAN_N*32 total
    int n = idx >> 5, grp = idx & 31;
    int dir = (n >= NN) ? 1 : 0;
    int node = dir ? n - NN : n;
    const float* W = dir ? Wb : Wf;
    int c1 = dir ? 2 : 1, c2 = dir ? 4 : 3;
    float f0 = x[node * 5], f1 = x[node * 5 + c1], f2 = x[node * 5 + c2];
    int j0 = grp * 8;
    float v[8];
#pragma unroll
    for (int j = 0; j < 8; j++)
      v[j] = f0 * W[j0 + j] + f1 * W[256 + j0 + j] + f2 * W[512 + j0 + j];
    uint4 u;
    u.x = pack2(v[0], v[1]);
    u.y = pack2(v[2], v[3]);
    u.z = pack2(v[4], v[5]);
    u.w = pack2(v[6], v[7]);
    *(uint4*)(out + (size_t)n * 256 + j0) = u;
    if (grp < 4) {  // head = grp: 3-FMA attention logits from WA table
      const float* ws = wa + dir * 24 + grp * 3;
      const float* wd = wa + dir * 24 + 12 + grp * 3;
      al_s[n * 4 + grp] = f0 * ws[0] + f1 * ws[1] + f2 * ws[2];
      al_d[n * 4 + grp] = f0 * wd[0] + f1 * wd[1] + f2 * wd[2];
    }
  }
}

__device__ __forceinline__ f32x2 unpk(unsigned w) {
  f32x2 v;
  v.x = bflo(w);
  v.y = bfhi(w);
  return v;
}

// ------- SpMM v7: full residency + uniform col loads --------------------------
// R5 post-mortem: occupancy pinned at 24% (~8 waves/CU vs VGPR cap of 24) ->
// latency under-hidden. Fix 1: 1600 blocks x 8 iters = all blocks resident at
// t~0 (6.25/CU ~ the 6-block VGPR cap); phase slice tightens to 1600 nodes/XCD
// (0.8MB << L2). Fix 2: col values are node-uniform -> load col[beg+c*8+k] as
// 8 uniform dword loads (HW broadcast) instead of per-lane gather + 8
// ds_bpermute redistribution; LDS-routed ops per chunk drop 17 -> 8 (w only).
// Online-softmax single-pass aggregation unchanged from v6.
template <int HH, int CC, int OUT_SPLIT>
__global__ __launch_bounds__(256) void spmm_kernel(const __hip_bfloat16* __restrict__ xp,
                                                   const float* __restrict__ als,
                                                   const float* __restrict__ ald,
                                                   const int* __restrict__ rp,
                                                   const int* __restrict__ col,
                                                   const float* __restrict__ biasf,
                                                   const float* __restrict__ biasb,
                                                   __hip_bfloat16* __restrict__ out_bf,
                                                   int do_elu) {
  constexpr int HC = HH * CC;    // channels per row: 256 or 128
  constexpr int RDW = HC / 2;    // dwords per row: 128 or 64
  constexpr int DL = RDW / 32;   // dwords per lane (32 lanes per node): 4 or 2
  int b = blockIdx.x;
  int xcd = b & 7;               // dispatch round-robins blocks over XCDs
  int bq = b >> 3;               // [0,200) within-XCD block index
  int dreg = xcd * 12800;        // contiguous 16-graph region per XCD
  int t = threadIdx.x;
  int wv = t >> 6, lane = t & 63;
  int sub = lane & 31, halfsel = lane >> 5;
  int lbase = lane & 32;
  int off_row = (dreg >= NN) ? NN : 0;       // uniform per block
  const float* bias = (dreg >= NN) ? biasb : biasf;
  int hch = (HH == 4) ? (sub >> 3) : 0;      // head owning this lane's channels
  int hat = (HH == 4) ? (sub & 3) : 0;       // head this lane covers in als gathers
  int eg  = (HH == 4) ? (sub >> 2) : (sub & 7);  // edge slot this lane covers
  const unsigned* xw = (const unsigned*)xp;
  float bv[2 * DL];
#pragma unroll
  for (int j = 0; j < 2 * DL; j++) bv[j] = bias[sub * 2 * DL + j];

#pragma unroll 1
  for (int it = 0; it < 8; ++it) {
    // temporal phasing: all blocks of an XCD cover the same 1600-node slice
    int d = dreg + it * 1600 + bq * 8 + wv * 2 + halfsel;
    int beg = rp[d];
    int deg = rp[d + 1] - beg;
    int degmax = max(deg, __shfl_xor(deg, 32));        // wave-uniform
    degmax = __builtin_amdgcn_readfirstlane(degmax);

    // node-level attention terms
    float ald_d = ald[(size_t)d * HH + hat];
    float selfw = __expf(leaky(als[(size_t)d * HH + hat] + ald_d));

    // self row (independent; issues early)
    unsigned swa[4] = {0u, 0u, 0u, 0u};
    {
      const unsigned* sp = xw + (size_t)d * RDW + sub * DL;
      if constexpr (DL == 4) {
        uint4 v4 = *(const uint4*)sp;
        swa[0] = v4.x; swa[1] = v4.y; swa[2] = v4.z; swa[3] = v4.w;
      } else {
        uint2 v2 = *(const uint2*)sp;
        swa[0] = v2.x; swa[1] = v2.y;
      }
    }

    f32x2 acc[DL];
#pragma unroll
    for (int j = 0; j < DL; j++) acc[j] = (f32x2)(0.f);
    float den = 0.f;

#pragma unroll
    for (int c = 0; c < 8; ++c) {  // 8-edge chunks, compile-time c
      if (c * 8 < degmax) {
        // cols: node-uniform -> 8 broadcast dword loads (no gather, no bpermute)
        // reads past rp[d+1] land in later rows / the +64 pad: clamped below,
        // and their w==0 so contribution is exactly 0.
        int cu[8];
#pragma unroll
        for (int k = 0; k < 8; ++k) {
          int cv = col[beg + c * 8 + k];
          cu[k] = min(max(cv, 0), NN - 1) + off_row;  // v_med3-style clamp
        }
        // als for this lane's (edge c*8+eg, head hat): one per-lane gather
        int cg = col[beg + c * 8 + eg];
        cg = min(max(cg, 0), NN - 1) + off_row;
        float alsv = als[(size_t)cg * HH + hat];
        // 8 rows in flight
        uint4 w8[8];  // DL==2 uses .x/.y only
#pragma unroll
        for (int k = 0; k < 8; ++k) {
          const unsigned* p = xw + (size_t)cu[k] * RDW + sub * DL;
          if constexpr (DL == 4) {
            w8[k] = *(const uint4*)p;
          } else {
            uint2 v2 = *(const uint2*)p;
            w8[k].x = v2.x;
            w8[k].y = v2.y;
          }
        }
        // consume: unnormalized weight (exp overlaps row-load latency)
        float w = 0.f;
        if (c * 8 + eg < deg) w = __expf(leaky(alsv + ald_d));
        if constexpr (HH == 4) den += w;                 // 32 lanes = 8e x 4h
        else den += (sub < 8) ? w : 0.f;                 // mask 4x redundancy
#pragma unroll
        for (int k = 0; k < 8; ++k) {  // padded slots: w==0 contributes 0
          float a = __shfl(w, lbase + ((HH == 4) ? (k * 4 + hch) : k));
          acc[0] += a * unpk(w8[k].x);
          acc[1] += a * unpk(w8[k].y);
          if constexpr (DL == 4) {
            acc[2] += a * unpk(w8[k].z);
            acc[3] += a * unpk(w8[k].w);
          }
        }
      }
    }
    for (int e = 64; e < degmax; ++e) {  // deg>64 fallback (practically never)
      if (e < deg) {
        int s = col[beg + e];
        s = (((unsigned)s < (unsigned)NN) ? s : 0) + off_row;
        float w = __expf(leaky(als[(size_t)s * HH + hat] + ald_d));
        if constexpr (HH == 4) den += (sub < 4) ? w : 0.f;
        else den += (sub == 0) ? w : 0.f;
        float a;
        if constexpr (HH == 4) a = __shfl(w, lbase + hch);
        else a = w;
        const unsigned* p = xw + (size_t)s * RDW + sub * DL;
        acc[0] += a * unpk(p[0]);
        acc[1] += a * unpk(p[1]);
        if constexpr (DL == 4) {
          acc[2] += a * unpk(p[2]);
          acc[3] += a * unpk(p[3]);
        }
      }
    }

    // reduce den per head, normalize once at the end
    if constexpr (HH == 4) {
      den += __shfl_xor(den, 4);
      den += __shfl_xor(den, 8);
      den += __shfl_xor(den, 16);
    } else {
      den += __shfl_xor(den, 1);
      den += __shfl_xor(den, 2);
      den += __shfl_xor(den, 4);
      den += __shfl_xor(den, 8);
      den += __shfl_xor(den, 16);
    }
    float inv = 1.f / (den + selfw + 1e-16f);
    float invc = inv, selfc = selfw;
    if constexpr (HH == 4) {  // broadcast head hch's values to channel lanes
      invc = __shfl(inv, lbase + hch);
      selfc = __shfl(selfw, lbase + hch);
    }

    float v[2 * DL];
#pragma unroll
    for (int j = 0; j < DL; j++) {
      f32x2 r = acc[j] + selfc * unpk(swa[j]);
      v[2 * j] = r.x * invc + bv[2 * j];
      v[2 * j + 1] = r.y * invc + bv[2 * j + 1];
    }
    if (do_elu) {
#pragma unroll
      for (int j = 0; j < 2 * DL; j++) v[j] = v[j] > 0.f ? v[j] : (__expf(v[j]) - 1.f);
    }
    if constexpr (OUT_SPLIT) {  // layer3: DL==2, write h_node half-row
      int nd = (d < NN) ? d : d - NN;
      int oo = (d < NN) ? 0 : 64;  // dword offset (128 bf16)
      uint2 u;
      u.x = pack2(v[0], v[1]);
      u.y = pack2(v[2], v[3]);
      *(uint2*)((unsigned*)out_bf + (size_t)nd * 128 + oo + sub * 2) = u;
    } else {
      uint4 u;
      u.x = pack2(v[0], v[1]);
      u.y = pack2(v[2], v[3]);
      u.z = pack2(v[4], v[5]);
      u.w = pack2(v[6], v[7]);
      *(uint4*)((unsigned*)out_bf + (size_t)d * RDW + sub * DL) = u;
    }
  }
}

// ------- weight cast + transpose + K-pad, two weight tensors in one launch -------
__global__ void castW2_kernel(const float* __restrict__ W0, const float* __restrict__ W1,
                              __hip_bfloat16* __restrict__ Wt0,
                              __hip_bfloat16* __restrict__ Wt1,
                              int K, int N, int Kp) {
  int idx = blockIdx.x * 256 + threadIdx.x;
  int tot = N * Kp;
  if (idx >= 2 * tot) return;
  const float* W = (idx < tot) ? W0 : W1;
  __hip_bfloat16* Wt = (idx < tot) ? Wt0 : Wt1;
  int i = (idx < tot) ? idx : idx - tot;
  int n = i / Kp, k = i % Kp;
  Wt[i] = (k < K) ? __float2bfloat16(W[(size_t)k * N + n]) : __float2bfloat16(0.f);
}

// ------- single weight cast + transpose + K-pad -------
__global__ void castW1_kernel(const float* __restrict__ W, __hip_bfloat16* __restrict__ Wt,
                              int K, int N, int Kp) {
  int idx = blockIdx.x * 256 + threadIdx.x;
  if (idx >= N * Kp) return;
  int n = idx / Kp, k = idx % Kp;
  Wt[idx] = (k < K) ? __float2bfloat16(W[(size_t)k * N + n]) : __float2bfloat16(0.f);
}

// ---------------- bf16 MFMA GEMM: C[M,N] = A[M,K] @ Bt[N,K]^T ----------------
template <int EPI, int ALH, int ALCC>
__global__ __launch_bounds__(256) void gemm_mfma(const __hip_bfloat16* __restrict__ A,
                                                 const __hip_bfloat16* __restrict__ Bt0,
                                                 const __hip_bfloat16* __restrict__ Bt1,
                                                 __hip_bfloat16* __restrict__ Cb,
                                                 const float* __restrict__ bias0,
                                                 const float* __restrict__ bias1,
                                                 const float* __restrict__ asv0,
                                                 const float* __restrict__ asv1,
                                                 const float* __restrict__ adv0,
                                                 const float* __restrict__ adv1,
                                                 float* __restrict__ al_s,
                                                 float* __restrict__ al_d,
                                                 int M, int N, int K, int Mhalf) {
  __shared__ __align__(16) __hip_bfloat16 As[128 * 32];
  __shared__ __align__(16) __hip_bfloat16 Bs[128 * 32];
  int t = threadIdx.x;
  int wave = t >> 6, lane = t & 63;
  int wm = (wave >> 1) * 64, wn = (wave & 1) * 64;
  int bm = blockIdx.y * 128, bn = blockIdx.x * 128;
  bool second = bm >= Mhalf;
  const __hip_bfloat16* Bt = second ? Bt1 : Bt0;
  const float* bias = second ? bias1 : bias0;
  const float* asv = second ? asv1 : asv0;
  const float* adv = second ? adv1 : adv0;

  int r0 = t >> 2, c0 = (t & 3) * 8;
  const __hip_bfloat16* Ag0 = A + (size_t)(bm + r0) * K + c0;
  const __hip_bfloat16* Ag1 = A + (size_t)(bm + r0 + 64) * K + c0;
  const __hip_bfloat16* Bg0 = Bt + (size_t)(bn + r0) * K + c0;
  const __hip_bfloat16* Bg1 = Bt + (size_t)(bn + r0 + 64) * K + c0;
  __hip_bfloat16* Asp0 = As + t * 8;
  __hip_bfloat16* Asp1 = As + 64 * 8 * 4 + t * 8;
  __hip_bfloat16* Bsp0 = Bs + t * 8;
  __hip_bfloat16* Bsp1 = Bs + 64 * 8 * 4 + t * 8;

  f32x4 acc[4][4];
#pragma unroll
  for (int i = 0; i < 4; i++)
#pragma unroll
    for (int j = 0; j < 4; j++) acc[i][j] = (f32x4)(0.f);

  int frag_off = (lane & 15) * 32 + (lane >> 4) * 8;
  const __hip_bfloat16* Ab = As + wm * 32 + frag_off;
  const __hip_bfloat16* Bb = Bs + wn * 32 + frag_off;

  for (int k0 = 0; k0 < K; k0 += 32) {
    __syncthreads();
    __builtin_amdgcn_global_load_lds((g_void*)(Ag0 + k0), (l_void*)Asp0, 16, 0, 0);
    __builtin_amdgcn_global_load_lds((g_void*)(Ag1 + k0), (l_void*)Asp1, 16, 0, 0);
    __builtin_amdgcn_global_load_lds((g_void*)(Bg0 + k0), (l_void*)Bsp0, 16, 0, 0);
    __builtin_amdgcn_global_load_lds((g_void*)(Bg1 + k0), (l_void*)Bsp1, 16, 0, 0);
    __syncthreads();
    bf16x8 af[4], bfr[4];
#pragma unroll
    for (int i = 0; i < 4; i++) af[i] = *(const bf16x8*)(Ab + i * 16 * 32);
#pragma unroll
    for (int j = 0; j < 4; j++) bfr[j] = *(const bf16x8*)(Bb + j * 16 * 32);
#pragma unroll
    for (int i = 0; i < 4; i++)
#pragma unroll
      for (int j = 0; j < 4; j++)
        acc[i][j] = __builtin_amdgcn_mfma_f32_16x16x32_bf16(af[i], bfr[j], acc[i][j], 0, 0, 0);
  }

  int cr = (lane >> 4) * 4, cc = lane & 15;

  if constexpr (ALH > 0) {
    int head = (bn + wn) / ALCC;
    float as_c[4], ad_c[4];
#pragma unroll
    for (int j = 0; j < 4; j++) {
      int colx = bn + wn + j * 16 + cc;
      as_c[j] = asv[colx];
      ad_c[j] = adv[colx];
    }
#pragma unroll
    for (int i = 0; i < 4; i++)
#pragma unroll
      for (int r = 0; r < 4; r++) {
        float ps = 0.f, pd = 0.f;
#pragma unroll
        for (int j = 0; j < 4; j++) {
          ps += acc[i][j][r] * as_c[j];
          pd += acc[i][j][r] * ad_c[j];
        }
        ps += __shfl_xor(ps, 1); pd += __shfl_xor(pd, 1);
        ps += __shfl_xor(ps, 2); pd += __shfl_xor(pd, 2);
        ps += __shfl_xor(ps, 4); pd += __shfl_xor(pd, 4);
        ps += __shfl_xor(ps, 8); pd += __shfl_xor(pd, 8);
        if ((lane & 15) == 0) {
          int row = bm + wm + i * 16 + cr + r;
          if (ALCC > 64) {
            atomicAdd(&al_s[row * ALH + head], ps);
            atomicAdd(&al_d[row * ALH + head], pd);
          } else {
            al_s[row * ALH + head] = ps;
            al_d[row * ALH + head] = pd;
          }
        }
      }
  }

#pragma unroll
  for (int i = 0; i < 4; i++)
#pragma unroll
    for (int j = 0; j < 4; j++) {
      int colx = bn + wn + j * 16 + cc;
      float bs = (EPI == 2) ? bias[colx] : 0.f;
#pragma unroll
      for (int r = 0; r < 4; r++) {
        float v = acc[i][j][r];
        if (EPI == 2) v = tanhf(v + bs);
        Cb[(size_t)(bm + wm + i * 16 + cr + r) * N + colx] = __float2bfloat16(v);
      }
    }
}

// ---------------- graph mean pooling (two stage, bf16 h_node) ----------------
__global__ void pool1_kernel(const __hip_bfloat16* __restrict__ h_node,
                             float* __restrict__ part) {
  int g = blockIdx.y, c = blockIdx.x, t = threadIdx.x;  // t over 128 dwords (256 ch)
  const unsigned* base = (const unsigned*)h_node + ((size_t)g * NPG + c * 100) * 128 + t;
  f32x2 s = (f32x2)(0.f);
  for (int i = 0; i < 100; i++) s += unpk(base[(size_t)i * 128]);
  part[(size_t)(g * 8 + c) * 256 + 2 * t] = s.x;
  part[(size_t)(g * 8 + c) * 256 + 2 * t + 1] = s.y;
}

__global__ void pool2_kernel(const float* __restrict__ part, float* __restrict__ g_pool) {
  int g = blockIdx.x, t = threadIdx.x;
  float s = 0.f;
  for (int c = 0; c < 8; c++) s += part[(size_t)(g * 8 + c) * 256 + t];
  g_pool[g * 256 + t] = s * (1.f / NPG);
}

// ---------------- build MLP input features (bf16 h_node -> bf16 feat) -------------
__global__ __launch_bounds__(256) void buildfeat_kernel(const __hip_bfloat16* __restrict__ h_node,
                                                        const float* __restrict__ g_pool,
                                                        const int* __restrict__ actions,
                                                        const float* __restrict__ tabu,
                                                        const int* __restrict__ batch,
                                                        __hip_bfloat16* __restrict__ feat) {
  int a = (blockIdx.x * blockDim.x + threadIdx.x) >> 6;
  int lane = threadIdx.x & 63;
  if (a >= NA) return;
  int n0 = actions[a * 2], n1 = actions[a * 2 + 1];
  int g = batch[n0];
  ushort4 v0 = *(const ushort4*)(h_node + (size_t)n0 * 256 + lane * 4);
  float4 vg = *(const float4*)(g_pool + (size_t)g * 256 + lane * 4);
  ushort4 v1 = *(const ushort4*)(h_node + (size_t)n1 * 256 + lane * 4);
  __hip_bfloat16* fr = feat + (size_t)a * KF;
  ushort4 ug = make_ushort4(f2b(vg.x), f2b(vg.y), f2b(vg.z), f2b(vg.w));
  *(ushort4*)(fr + lane * 4) = v0;
  *(ushort4*)(fr + 256 + lane * 4) = ug;
  *(ushort4*)(fr + 512 + lane * 4) = v1;
  *(ushort4*)(fr + 768 + lane * 4) = ug;
  if (lane < 8) {
    float t0 = (lane == 0) ? tabu[a] : 0.f;
    ushort4 u = make_ushort4(f2b(t0), 0, 0, 0);
    *(ushort4*)(fr + 1024 + lane * 4) = u;
  }
}

// ------- fused head: scores = y @ W4 + b4, then log-softmax + entropy per graph ----
__global__ __launch_bounds__(256) void head_kernel(const __hip_bfloat16* __restrict__ y,
                                                   const float* __restrict__ W4,
                                                   const float* __restrict__ b4,
                                                   float* __restrict__ out) {
  __shared__ float sc[64];
  int g = blockIdx.x;  // graph
  int t = threadIdx.x;
  int a = t >> 2, sub = t & 3;
  int aid = g * 64 + a;
  const unsigned* row = (const unsigned*)(y + (size_t)aid * 256) + sub * 32;
  const float* w = W4 + sub * 64;
  float s = 0.f;
#pragma unroll
  for (int q = 0; q < 32; q++) {
    s += bflo(row[q]) * w[2 * q] + bfhi(row[q]) * w[2 * q + 1];
  }
  s += __shfl_xor(s, 1);
  s += __shfl_xor(s, 2);
  if (sub == 0) sc[a] = s + b4[0];
  __syncthreads();
  if (t < 64) {
    float v = sc[t];
    float m = v;
    for (int off = 1; off < 64; off <<= 1) m = fmaxf(m, __shfl_xor(m, off));
    float ex = expf(v - m);
    float sum = ex;
    for (int off = 1; off < 64; off <<= 1) sum += __shfl_xor(sum, off);
    float lp = v - m - logf(sum);
    out[g * 64 + t] = lp;
    float pe = (ex / sum) * lp;
    for (int off = 1; off < 64; off <<= 1) pe += __shfl_xor(pe, off);
    if (t == 0) out[BB * APG + g] = -pe;
  }
}

extern "C" void kernel_launch(void* const* d_in, const int* in_sizes, int n_in,
                              void* d_out, int out_size, void* d_ws, size_t ws_size,
                              hipStream_t stream) {
  const float* x = (const float*)d_in[0];
  const int* ei = (const int*)d_in[1];
  const int* batch = (const int*)d_in[2];
  const int* actions = (const int*)d_in[3];
  const float* tabu = (const float*)d_in[4];
  const float* fW[3] = {(const float*)d_in[5], (const float*)d_in[9], (const float*)d_in[13]};
  const float* fas[3] = {(const float*)d_in[6], (const float*)d_in[10], (const float*)d_in[14]};
  const float* fad[3] = {(const float*)d_in[7], (const float*)d_in[11], (const float*)d_in[15]};
  const float* fb[3] = {(const float*)d_in[8], (const float*)d_in[12], (const float*)d_in[16]};
  const float* bW[3] = {(const float*)d_in[17], (const float*)d_in[21], (const float*)d_in[25]};
  const float* bas[3] = {(const float*)d_in[18], (const float*)d_in[22], (const float*)d_in[26]};
  const float* bad[3] = {(const float*)d_in[19], (const float*)d_in[23], (const float*)d_in[27]};
  const float* bb[3] = {(const float*)d_in[20], (const float*)d_in[24], (const float*)d_in[28]};
  const float* pW1 = (const float*)d_in[29];
  const float* pb1 = (const float*)d_in[30];
  const float* pW2 = (const float*)d_in[31];
  const float* pb2 = (const float*)d_in[32];
  const float* pW3 = (const float*)d_in[33];
  const float* pb3 = (const float*)d_in[34];
  const float* pW4 = (const float*)d_in[35];
  const float* pb4 = (const float*)d_in[36];
  float* out = (float*)d_out;

  char* ws = (char*)d_ws;
  size_t o = 0;
  auto alloc = [&](size_t bytes) -> void* {
    o = (o + 255) & ~(size_t)255;
    void* p = ws + o;
    o += bytes;
    return p;
  };
  int* cnt = (int*)alloc((size_t)4 * NN * 4);  // cnt[2NN] + pos[2NN]
  int* rp = (int*)alloc((size_t)(SCAN_N + 1) * 4);
  int* col = (int*)alloc(((size_t)2 * EE + 64) * 4);
  int* bsum = (int*)alloc(128 * 4);
  int* boff = (int*)alloc(128 * 4);
  float* al_s = (float*)alloc((size_t)SCAN_N * 4 * 4);  // al_s + al_d contiguous
  float* al_d = (float*)alloc((size_t)SCAN_N * 4 * 4);
  __hip_bfloat16* xp = (__hip_bfloat16*)alloc((size_t)SCAN_N * 256 * 2);    // both dirs
  __hip_bfloat16* bufA = (__hip_bfloat16*)alloc((size_t)SCAN_N * 256 * 2);  // spmm out
  __hip_bfloat16* h_node = (__hip_bfloat16*)alloc((size_t)NN * 256 * 2);
  __hip_bfloat16* wt0 = (__hip_bfloat16*)alloc((size_t)256 * KF * 2);
  __hip_bfloat16* wt1 = (__hip_bfloat16*)alloc((size_t)256 * KF * 2);
  float* part = (float*)alloc((size_t)BB * 8 * 256 * 4);
  float* g_pool = (float*)alloc((size_t)BB * 256 * 4);
  float* wa = (float*)alloc(64 * 4);
  // MLP scratch aliased onto xp (dead after last spmm)
  __hip_bfloat16* feat = xp;
  __hip_bfloat16* y1 = feat + (size_t)NA * KF;
  __hip_bfloat16* y2 = y1 + (size_t)NA * 256;

  // --- CSR build ---
  hipMemsetAsync(cnt, 0, (size_t)4 * NN * 4, stream);
  count_kernel<<<(EE + 255) / 256, 256, 0, stream>>>(ei, cnt);
  scan1_kernel<<<SCAN_N / 1024, 256, 0, stream>>>(cnt, rp, bsum);
  scan2_kernel<<<1, 128, 0, stream>>>(bsum, boff, rp);
  scan3_kernel<<<SCAN_N / 1024, 256, 0, stream>>>(rp, boff);
  fill_kernel<<<(EE + 255) / 256, 256, 0, stream>>>(ei, rp, cnt + 2 * NN, col);

  const int nwb = 1600;  // spmm blocks (64 nodes each, 8 phased iters, full residency)

  // layer 1 (fin=3, H=4, C=64) both dirs: WA table + fused linear/al logits
  precomp_kernel<<<12, 256, 0, stream>>>(fW[0], bW[0], fas[0], fad[0], bas[0], bad[0], wa);
  lin1_kernel<<<1600, 256, 0, stream>>>(x, fW[0], bW[0], wa, xp, al_s, al_d);
  spmm_kernel<4, 64, 0><<<nwb, 256, 0, stream>>>(xp, al_s, al_d, rp, col,
                                                 fb[0], bb[0], bufA, 1);
  // layer 2 (256 -> H4C64) both dirs, al fused into GEMM epilogue
  castW2_kernel<<<(2 * 256 * 256 + 255) / 256, 256, 0, stream>>>(fW[1], bW[1], wt0, wt1,
                                                                 256, 256, 256);
  gemm_mfma<1, 4, 64><<<dim3(2, SCAN_N / 128), 256, 0, stream>>>(
      bufA, wt0, wt1, xp, nullptr, nullptr, fas[1], bas[1], fad[1], bad[1],
      al_s, al_d, SCAN_N, 256, 256, NN);
  spmm_kernel<4, 64, 0><<<nwb, 256, 0, stream>>>(xp, al_s, al_d, rp, col,
                                                 fb[1], bb[1], bufA, 1);
  // layer 3 (256 -> H1C128, no elu) both dirs -> h_node halves (bf16); al fused
  castW2_kernel<<<(2 * 128 * 256 + 255) / 256, 256, 0, stream>>>(fW[2], bW[2], wt0, wt1,
                                                                 256, 128, 256);
  hipMemsetAsync(al_s, 0, (size_t)2 * SCAN_N * 4, stream);  // al_s + al_d (contiguous)
  gemm_mfma<1, 1, 128><<<dim3(1, SCAN_N / 128), 256, 0, stream>>>(
      bufA, wt0, wt1, xp, nullptr, nullptr, fas[2], bas[2], fad[2], bad[2],
      al_s, al_d, SCAN_N, 128, 256, NN);
  spmm_kernel<1, 128, 1><<<nwb, 256, 0, stream>>>(xp, al_s, al_d, rp, col,
                                                  fb[2], bb[2], h_node, 0);

  pool1_kernel<<<dim3(8, BB), 128, 0, stream>>>(h_node, part);
  pool2_kernel<<<BB, 256, 0, stream>>>(part, g_pool);

  // --- MLP head via MFMA ---
  buildfeat_kernel<<<NA / 4, 256, 0, stream>>>(h_node, g_pool, actions, tabu, batch, feat);
  castW1_kernel<<<(256 * KF + 255) / 256, 256, 0, stream>>>(pW1, wt0, 1025, 256, KF);
  gemm_mfma<2, 0, 64><<<dim3(2, NA / 128), 256, 0, stream>>>(
      feat, wt0, wt0, y1, pb1, pb1, nullptr, nullptr, nullptr, nullptr,
      nullptr, nullptr, NA, 256, KF, 1 << 30);
  castW2_kernel<<<(2 * 256 * 256 + 255) / 256, 256, 0, stream>>>(pW2, pW3, wt0, wt1,
                                                                 256, 256, 256);
  gemm_mfma<2, 0, 64><<<dim3(2, NA / 128), 256, 0, stream>>>(
      y1, wt0, wt0, y2, pb2, pb2, nullptr, nullptr, nullptr, nullptr,
      nullptr, nullptr, NA, 256, 256, 1 << 30);
  gemm_mfma<2, 0, 64><<<dim3(2, NA / 128), 256, 0, stream>>>(
      y2, wt1, wt1, y1, pb3, pb3, nullptr, nullptr, nullptr, nullptr,
      nullptr, nullptr, NA, 256, 256, 1 << 30);
  head_kernel<<<BB, 256, 0, stream>>>(y1, pW4, pb4, out);
}

// Round 8
// 498.155 us; speedup vs baseline: 1.0465x; 1.0465x over previous
//
#include <hip/hip_runtime.h>
#include <hip/hip_bf16.h>
#include <math.h>

constexpr int NN  = 51200;   // total nodes
constexpr int EE  = 409600;  // edges (without self loops)
constexpr int BB  = 64;      // graphs
constexpr int APG = 64;      // actions per graph
constexpr int NPG = 800;     // nodes per graph
constexpr int SCAN_N = 2 * NN;
constexpr int NA = BB * APG; // 4096 actions
constexpr int KF = 1056;     // padded MLP input dim (1025 -> 33*32)

typedef __bf16 bf16x8 __attribute__((ext_vector_type(8)));
typedef float f32x4 __attribute__((ext_vector_type(4)));
typedef float f32x2 __attribute__((ext_vector_type(2)));
typedef __attribute__((address_space(1))) const void g_void;
typedef __attribute__((address_space(3))) void l_void;

__device__ __forceinline__ float leaky(float x) { return fmaxf(x, 0.2f * x); }
__device__ __forceinline__ float bflo(unsigned w) { return __uint_as_float(w << 16); }
__device__ __forceinline__ float bfhi(unsigned w) { return __uint_as_float(w & 0xffff0000u); }
__device__ __forceinline__ unsigned short f2b(float x) {
  __hip_bfloat16 h = __float2bfloat16(x);
  unsigned short u;
  __builtin_memcpy(&u, &h, 2);
  return u;
}
__device__ __forceinline__ unsigned pack2(float a, float b) {
  return (unsigned)f2b(a) | ((unsigned)f2b(b) << 16);
}

// ---------------- CSR build ----------------
__global__ void count_kernel(const int* __restrict__ ei, int* cnt) {
  int e = blockIdx.x * blockDim.x + threadIdx.x;
  if (e >= EE) return;
  int s = ei[e], d = ei[EE + e];
  atomicAdd(&cnt[d], 1);
  atomicAdd(&cnt[NN + s], 1);
}

__global__ __launch_bounds__(256) void scan1_kernel(const int* __restrict__ cnt,
                                                    int* __restrict__ rp,
                                                    int* __restrict__ bsum) {
  __shared__ int wsum[4];
  int b = blockIdx.x, t = threadIdx.x;
  int base = b * 1024 + t * 4;
  int4 v = *(const int4*)(cnt + base);
  int s = v.x + v.y + v.z + v.w;
  int lane = t & 63, wv = t >> 6;
  int incl = s;
  for (int off = 1; off < 64; off <<= 1) {
    int u = __shfl_up(incl, off);
    if (lane >= off) incl += u;
  }
  if (lane == 63) wsum[wv] = incl;
  __syncthreads();
  int woff = 0;
  for (int i = 0; i < wv; i++) woff += wsum[i];
  int excl = woff + incl - s;
  rp[base] = excl;
  rp[base + 1] = excl + v.x;
  rp[base + 2] = excl + v.x + v.y;
  rp[base + 3] = excl + v.x + v.y + v.z;
  if (t == 255) bsum[b] = woff + incl;
}

__global__ void scan2_kernel(const int* __restrict__ bsum, int* __restrict__ boff,
                             int* __restrict__ rp) {
  __shared__ int w0;
  int t = threadIdx.x;  // 128 threads
  int v = (t < 100) ? bsum[t] : 0;
  int lane = t & 63;
  int incl = v;
  for (int off = 1; off < 64; off <<= 1) {
    int u = __shfl_up(incl, off);
    if (lane >= off) incl += u;
  }
  if (t == 63) w0 = incl;
  __syncthreads();
  int excl = incl - v + ((t >= 64) ? w0 : 0);
  if (t < 100) boff[t] = excl;
  if (t == 99) rp[SCAN_N] = excl + v;
}

__global__ __launch_bounds__(256) void scan3_kernel(int* __restrict__ rp,
                                                    const int* __restrict__ boff) {
  int b = blockIdx.x;
  int off = boff[b];
  int i = b * 1024 + threadIdx.x * 4;
  int4 v = *(int4*)(rp + i);
  v.x += off; v.y += off; v.z += off; v.w += off;
  *(int4*)(rp + i) = v;
}

__global__ void fill_kernel(const int* __restrict__ ei, const int* __restrict__ rp,
                            int* pos, int* __restrict__ col) {
  int e = blockIdx.x * blockDim.x + threadIdx.x;
  if (e >= EE) return;
  int s = ei[e], d = ei[EE + e];
  int p = atomicAdd(&pos[d], 1);
  col[rp[d] + p] = s;
  int q = atomicAdd(&pos[NN + s], 1);
  col[rp[NN + s] + q] = d;
}

// ------- WA precompute: wa[dir*24 + sd*12 + h*3 + c] = W[c]·a[h] over 64 ch -------
__global__ __launch_bounds__(256) void precomp_kernel(const float* __restrict__ Wf,
                                                      const float* __restrict__ Wb,
                                                      const float* __restrict__ asf,
                                                      const float* __restrict__ adf,
                                                      const float* __restrict__ asb,
                                                      const float* __restrict__ adb,
                                                      float* __restrict__ wa) {
  int wave = (blockIdx.x * blockDim.x + threadIdx.x) >> 6;  // 0..47
  int lane = threadIdx.x & 63;
  if (wave >= 48) return;
  int dir = wave / 24, sd = (wave / 12) % 2, h = (wave / 3) % 4, c = wave % 3;
  const float* W = dir ? Wb : Wf;
  const float* a = dir ? (sd ? adb : asb) : (sd ? adf : asf);
  float v = W[c * 256 + h * 64 + lane] * a[h * 64 + lane];
  for (int off = 1; off < 64; off <<= 1) v += __shfl_xor(v, off);
  if (lane == 0) wa[wave] = v;
}

// ------- layer-1 linear + fused al logits (8 ch/thread, both dirs) ----------
// 1600 blocks x 8 iters (R1-isolated win: 12800 trivial blocks = launch floor)
__global__ __launch_bounds__(256) void lin1_kernel(const float* __restrict__ x,
                                                   const float* __restrict__ Wf,
                                                   const float* __restrict__ Wb,
                                                   const float* __restrict__ wa,
                                                   __hip_bfloat16* __restrict__ out,
                                                   float* __restrict__ al_s,
                                                   float* __restrict__ al_d) {
#pragma unroll 1
  for (int itq = 0; itq < 8; ++itq) {
    int idx = blockIdx.x * 2048 + itq * 256 + threadIdx.x;  // SCAN_N*32 total
    int n = idx >> 5, grp = idx & 31;
    int dir = (n >= NN) ? 1 : 0;
    int node = dir ? n - NN : n;
    const float* W = dir ? Wb : Wf;
    int c1 = dir ? 2 : 1, c2 = dir ? 4 : 3;
    float f0 = x[node * 5], f1 = x[node * 5 + c1], f2 = x[node * 5 + c2];
    int j0 = grp * 8;
    float v[8];
#pragma unroll
    for (int j = 0; j < 8; j++)
      v[j] = f0 * W[j0 + j] + f1 * W[256 + j0 + j] + f2 * W[512 + j0 + j];
    uint4 u;
    u.x = pack2(v[0], v[1]);
    u.y = pack2(v[2], v[3]);
    u.z = pack2(v[4], v[5]);
    u.w = pack2(v[6], v[7]);
    *(uint4*)(out + (size_t)n * 256 + j0) = u;
    if (grp < 4) {  // head = grp: 3-FMA attention logits from WA table
      const float* ws = wa + dir * 24 + grp * 3;
      const float* wd = wa + dir * 24 + 12 + grp * 3;
      al_s[n * 4 + grp] = f0 * ws[0] + f1 * ws[1] + f2 * ws[2];
      al_d[n * 4 + grp] = f0 * wd[0] + f1 * wd[1] + f2 * wd[2];
    }
  }
}

__device__ __forceinline__ f32x2 unpk(unsigned w) {
  f32x2 v;
  v.x = bflo(w);
  v.y = bfhi(w);
  return v;
}

// ------- SpMM v6 (reverted from v7): single-pass online-softmax, 3200 blocks ------
// R6 post-mortem: v7's "full residency" (1600 blocks) let blocks drift out of
// phase -> FETCH +7MB, dur +12us; uniform col loads re-read col 9x/chunk vs
// v6's once/node. v6 (this code) measured 53.1us/dispatch: col loaded once
// (cA/cB), distributed via shfl; als gather + 8 row loads issue together;
// normalization deferred to epilogue. XCD temporal phasing (1.6MB <= L2).
template <int HH, int CC, int OUT_SPLIT>
__global__ __launch_bounds__(256) void spmm_kernel(const __hip_bfloat16* __restrict__ xp,
                                                   const float* __restrict__ als,
                                                   const float* __restrict__ ald,
                                                   const int* __restrict__ rp,
                                                   const int* __restrict__ col,
                                                   const float* __restrict__ biasf,
                                                   const float* __restrict__ biasb,
                                                   __hip_bfloat16* __restrict__ out_bf,
                                                   int do_elu) {
  constexpr int HC = HH * CC;    // channels per row: 256 or 128
  constexpr int RDW = HC / 2;    // dwords per row: 128 or 64
  constexpr int DL = RDW / 32;   // dwords per lane (32 lanes per node): 4 or 2
  int b = blockIdx.x;
  int xcd = b & 7;               // dispatch round-robins blocks over XCDs
  int bq = b >> 3;               // [0,400) within-XCD block index
  int dreg = xcd * 12800;        // contiguous 16-graph region per XCD
  int t = threadIdx.x;
  int wv = t >> 6, lane = t & 63;
  int sub = lane & 31, halfsel = lane >> 5;
  int lbase = lane & 32;
  int off_row = (dreg >= NN) ? NN : 0;       // uniform per block
  const float* bias = (dreg >= NN) ? biasb : biasf;
  int hch = (HH == 4) ? (sub >> 3) : 0;      // head owning this lane's channels
  int hat = (HH == 4) ? (sub & 3) : 0;       // head this lane covers in als gathers
  int eg  = (HH == 4) ? (sub >> 2) : (sub & 7);  // edge slot this lane covers
  const unsigned* xw = (const unsigned*)xp;
  float bv[2 * DL];
#pragma unroll
  for (int j = 0; j < 2 * DL; j++) bv[j] = bias[sub * 2 * DL + j];

#pragma unroll 1
  for (int it = 0; it < 4; ++it) {
    int d = dreg + it * 3200 + bq * 8 + wv * 2 + halfsel;
    int beg = rp[d];
    int deg = rp[d + 1] - beg;
    int degmax = max(deg, __shfl_xor(deg, 32));        // wave-uniform
    degmax = __builtin_amdgcn_readfirstlane(degmax);

    // node-level attention terms
    float ald_d = ald[(size_t)d * HH + hat];
    float selfw = __expf(leaky(als[(size_t)d * HH + hat] + ald_d));

    // col for edges 0..63: lane-resident (clamped; garbage-safe for deg==0)
    int e0 = (sub < deg) ? sub : (deg - 1);
    e0 = (e0 < 0) ? 0 : e0;
    int cA = col[beg + e0];
    cA = (((unsigned)cA < (unsigned)NN) ? cA : 0) + off_row;
    int cB = off_row;
    if (degmax > 32) {
      int e1 = (32 + sub < deg) ? (32 + sub) : (deg - 1);
      e1 = (e1 < 0) ? 0 : e1;
      cB = col[beg + e1];
      cB = (((unsigned)cB < (unsigned)NN) ? cB : 0) + off_row;
    }

    // self row (independent; issues early)
    unsigned swa[4] = {0u, 0u, 0u, 0u};
    {
      const unsigned* sp = xw + (size_t)d * RDW + sub * DL;
      if constexpr (DL == 4) {
        uint4 v4 = *(const uint4*)sp;
        swa[0] = v4.x; swa[1] = v4.y; swa[2] = v4.z; swa[3] = v4.w;
      } else {
        uint2 v2 = *(const uint2*)sp;
        swa[0] = v2.x; swa[1] = v2.y;
      }
    }

    f32x2 acc[DL];
#pragma unroll
    for (int j = 0; j < DL; j++) acc[j] = (f32x2)(0.f);
    float den = 0.f;

#pragma unroll
    for (int c = 0; c < 8; ++c) {  // 8-edge chunks, compile-time c
      if (c * 8 < degmax) {
        // issue: als for (edge c*8+eg, head hat) -- 32 lanes cover 8x4
        int sg = __shfl((c < 4) ? cA : cB, lbase + (c & 3) * 8 + eg);
        float alsv = als[(size_t)sg * HH + hat];
        // issue: 8 rows in flight
        uint4 w8[8];  // DL==2 uses .x/.y only
#pragma unroll
        for (int k = 0; k < 8; ++k) {
          int s = __shfl((c < 4) ? cA : cB, lbase + (c & 3) * 8 + k);
          const unsigned* p = xw + (size_t)s * RDW + sub * DL;
          if constexpr (DL == 4) {
            w8[k] = *(const uint4*)p;
          } else {
            uint2 v2 = *(const uint2*)p;
            w8[k].x = v2.x;
            w8[k].y = v2.y;
          }
        }
        // consume: unnormalized weight (exp overlaps row-load latency)
        float w = 0.f;
        if (c * 8 + eg < deg) w = __expf(leaky(alsv + ald_d));
        if constexpr (HH == 4) den += w;                 // 32 lanes = 8e x 4h
        else den += (sub < 8) ? w : 0.f;                 // mask 4x redundancy
#pragma unroll
        for (int k = 0; k < 8; ++k) {  // padded slots: w==0 contributes 0
          float a = __shfl(w, lbase + ((HH == 4) ? (k * 4 + hch) : k));
          acc[0] += a * unpk(w8[k].x);
          acc[1] += a * unpk(w8[k].y);
          if constexpr (DL == 4) {
            acc[2] += a * unpk(w8[k].z);
            acc[3] += a * unpk(w8[k].w);
          }
        }
      }
    }
    for (int e = 64; e < degmax; ++e) {  // deg>64 fallback (practically never)
      if (e < deg) {
        int s = col[beg + e];
        s = (((unsigned)s < (unsigned)NN) ? s : 0) + off_row;
        float w = __expf(leaky(als[(size_t)s * HH + hat] + ald_d));
        if constexpr (HH == 4) den += (sub < 4) ? w : 0.f;
        else den += (sub == 0) ? w : 0.f;
        float a;
        if constexpr (HH == 4) a = __shfl(w, lbase + hch);
        else a = w;
        const unsigned* p = xw + (size_t)s * RDW + sub * DL;
        acc[0] += a * unpk(p[0]);
        acc[1] += a * unpk(p[1]);
        if constexpr (DL == 4) {
          acc[2] += a * unpk(p[2]);
          acc[3] += a * unpk(p[3]);
        }
      }
    }

    // reduce den per head, normalize once at the end
    if constexpr (HH == 4) {
      den += __shfl_xor(den, 4);
      den += __shfl_xor(den, 8);
      den += __shfl_xor(den, 16);
    } else {
      den += __shfl_xor(den, 1);
      den += __shfl_xor(den, 2);
      den += __shfl_xor(den, 4);
      den += __shfl_xor(den, 8);
      den += __shfl_xor(den, 16);
    }
    float inv = 1.f / (den + selfw + 1e-16f);
    float invc = inv, selfc = selfw;
    if constexpr (HH == 4) {  // broadcast head hch's values to channel lanes
      invc = __shfl(inv, lbase + hch);
      selfc = __shfl(selfw, lbase + hch);
    }

    float v[2 * DL];
#pragma unroll
    for (int j = 0; j < DL; j++) {
      f32x2 r = acc[j] + selfc * unpk(swa[j]);
      v[2 * j] = r.x * invc + bv[2 * j];
      v[2 * j + 1] = r.y * invc + bv[2 * j + 1];
    }
    if (do_elu) {
#pragma unroll
      for (int j = 0; j < 2 * DL; j++) v[j] = v[j] > 0.f ? v[j] : (__expf(v[j]) - 1.f);
    }
    if constexpr (OUT_SPLIT) {  // layer3: DL==2, write h_node half-row
      int nd = (d < NN) ? d : d - NN;
      int oo = (d < NN) ? 0 : 64;  // dword offset (128 bf16)
      uint2 u;
      u.x = pack2(v[0], v[1]);
      u.y = pack2(v[2], v[3]);
      *(uint2*)((unsigned*)out_bf + (size_t)nd * 128 + oo + sub * 2) = u;
    } else {
      uint4 u;
      u.x = pack2(v[0], v[1]);
      u.y = pack2(v[2], v[3]);
      u.z = pack2(v[4], v[5]);
      u.w = pack2(v[6], v[7]);
      *(uint4*)((unsigned*)out_bf + (size_t)d * RDW + sub * DL) = u;
    }
  }
}

// ------- weight cast + transpose + K-pad, two weight tensors in one launch -------
__global__ void castW2_kernel(const float* __restrict__ W0, const float* __restrict__ W1,
                              __hip_bfloat16* __restrict__ Wt0,
                              __hip_bfloat16* __restrict__ Wt1,
                              int K, int N, int Kp) {
  int idx = blockIdx.x * 256 + threadIdx.x;
  int tot = N * Kp;
  if (idx >= 2 * tot) return;
  const float* W = (idx < tot) ? W0 : W1;
  __hip_bfloat16* Wt = (idx < tot) ? Wt0 : Wt1;
  int i = (idx < tot) ? idx : idx - tot;
  int n = i / Kp, k = i % Kp;
  Wt[i] = (k < K) ? __float2bfloat16(W[(size_t)k * N + n]) : __float2bfloat16(0.f);
}

// ------- single weight cast + transpose + K-pad -------
__global__ void castW1_kernel(const float* __restrict__ W, __hip_bfloat16* __restrict__ Wt,
                              int K, int N, int Kp) {
  int idx = blockIdx.x * 256 + threadIdx.x;
  if (idx >= N * Kp) return;
  int n = idx / Kp, k = idx % Kp;
  Wt[idx] = (k < K) ? __float2bfloat16(W[(size_t)k * N + n]) : __float2bfloat16(0.f);
}

// ---------------- bf16 MFMA GEMM: C[M,N] = A[M,K] @ Bt[N,K]^T ----------------
// SWZ_GX > 0 (layer2/3 over SCAN_N rows): XCD-aligned block swizzle so each
// XCD's gemm blocks cover the SAME 12800-row band its spmm blocks read/write
// -> bufA reads + xp writes stay in XCD-local L2 across the spmm/gemm chain.
// lin = bx + SWZ_GX*by (HW round-robins linear id over 8 XCDs); bijective.
template <int EPI, int ALH, int ALCC, int SWZ_GX>
__global__ __launch_bounds__(256) void gemm_mfma(const __hip_bfloat16* __restrict__ A,
                                                 const __hip_bfloat16* __restrict__ Bt0,
                                                 const __hip_bfloat16* __restrict__ Bt1,
                                                 __hip_bfloat16* __restrict__ Cb,
                                                 const float* __restrict__ bias0,
                                                 const float* __restrict__ bias1,
                                                 const float* __restrict__ asv0,
                                                 const float* __restrict__ asv1,
                                                 const float* __restrict__ adv0,
                                                 const float* __restrict__ adv1,
                                                 float* __restrict__ al_s,
                                                 float* __restrict__ al_d,
                                                 int M, int N, int K, int Mhalf) {
  __shared__ __align__(16) __hip_bfloat16 As[128 * 32];
  __shared__ __align__(16) __hip_bfloat16 Bs[128 * 32];
  int t = threadIdx.x;
  int wave = t >> 6, lane = t & 63;
  int wm = (wave >> 1) * 64, wn = (wave & 1) * 64;
  int bm, bn;
  if constexpr (SWZ_GX > 0) {
    int lin = blockIdx.x + SWZ_GX * blockIdx.y;  // x-major linear workgroup id
    int xcd = lin & 7, q = lin >> 3;             // q in [0, 100*SWZ_GX)
    bn = (q / 100) * 128;
    bm = (xcd * 100 + (q % 100)) * 128;          // XCD k owns rows [k*12800, ...)
  } else {
    bm = blockIdx.y * 128;
    bn = blockIdx.x * 128;
  }
  bool second = bm >= Mhalf;
  const __hip_bfloat16* Bt = second ? Bt1 : Bt0;
  const float* bias = second ? bias1 : bias0;
  const float* asv = second ? asv1 : asv0;
  const float* adv = second ? adv1 : adv0;

  int r0 = t >> 2, c0 = (t & 3) * 8;
  const __hip_bfloat16* Ag0 = A + (size_t)(bm + r0) * K + c0;
  const __hip_bfloat16* Ag1 = A + (size_t)(bm + r0 + 64) * K + c0;
  const __hip_bfloat16* Bg0 = Bt + (size_t)(bn + r0) * K + c0;
  const __hip_bfloat16* Bg1 = Bt + (size_t)(bn + r0 + 64) * K + c0;
  __hip_bfloat16* Asp0 = As + t * 8;
  __hip_bfloat16* Asp1 = As + 64 * 8 * 4 + t * 8;
  __hip_bfloat16* Bsp0 = Bs + t * 8;
  __hip_bfloat16* Bsp1 = Bs + 64 * 8 * 4 + t * 8;

  f32x4 acc[4][4];
#pragma unroll
  for (int i = 0; i < 4; i++)
#pragma unroll
    for (int j = 0; j < 4; j++) acc[i][j] = (f32x4)(0.f);

  int frag_off = (lane & 15) * 32 + (lane >> 4) * 8;
  const __hip_bfloat16* Ab = As + wm * 32 + frag_off;
  const __hip_bfloat16* Bb = Bs + wn * 32 + frag_off;

  for (int k0 = 0; k0 < K; k0 += 32) {
    __syncthreads();
    __builtin_amdgcn_global_load_lds((g_void*)(Ag0 + k0), (l_void*)Asp0, 16, 0, 0);
    __builtin_amdgcn_global_load_lds((g_void*)(Ag1 + k0), (l_void*)Asp1, 16, 0, 0);
    __builtin_amdgcn_global_load_lds((g_void*)(Bg0 + k0), (l_void*)Bsp0, 16, 0, 0);
    __builtin_amdgcn_global_load_lds((g_void*)(Bg1 + k0), (l_void*)Bsp1, 16, 0, 0);
    __syncthreads();
    bf16x8 af[4], bfr[4];
#pragma unroll
    for (int i = 0; i < 4; i++) af[i] = *(const bf16x8*)(Ab + i * 16 * 32);
#pragma unroll
    for (int j = 0; j < 4; j++) bfr[j] = *(const bf16x8*)(Bb + j * 16 * 32);
#pragma unroll
    for (int i = 0; i < 4; i++)
#pragma unroll
      for (int j = 0; j < 4; j++)
        acc[i][j] = __builtin_amdgcn_mfma_f32_16x16x32_bf16(af[i], bfr[j], acc[i][j], 0, 0, 0);
  }

  int cr = (lane >> 4) * 4, cc = lane & 15;

  if constexpr (ALH > 0) {
    int head = (bn + wn) / ALCC;
    float as_c[4], ad_c[4];
#pragma unroll
    for (int j = 0; j < 4; j++) {
      int colx = bn + wn + j * 16 + cc;
      as_c[j] = asv[colx];
      ad_c[j] = adv[colx];
    }
#pragma unroll
    for (int i = 0; i < 4; i++)
#pragma unroll
      for (int r = 0; r < 4; r++) {
        float ps = 0.f, pd = 0.f;
#pragma unroll
        for (int j = 0; j < 4; j++) {
          ps += acc[i][j][r] * as_c[j];
          pd += acc[i][j][r] * ad_c[j];
        }
        ps += __shfl_xor(ps, 1); pd += __shfl_xor(pd, 1);
        ps += __shfl_xor(ps, 2); pd += __shfl_xor(pd, 2);
        ps += __shfl_xor(ps, 4); pd += __shfl_xor(pd, 4);
        ps += __shfl_xor(ps, 8); pd += __shfl_xor(pd, 8);
        if ((lane & 15) == 0) {
          int row = bm + wm + i * 16 + cr + r;
          if (ALCC > 64) {
            atomicAdd(&al_s[row * ALH + head], ps);
            atomicAdd(&al_d[row * ALH + head], pd);
          } else {
            al_s[row * ALH + head] = ps;
            al_d[row * ALH + head] = pd;
          }
        }
      }
  }

#pragma unroll
  for (int i = 0; i < 4; i++)
#pragma unroll
    for (int j = 0; j < 4; j++) {
      int colx = bn + wn + j * 16 + cc;
      float bs = (EPI == 2) ? bias[colx] : 0.f;
#pragma unroll
      for (int r = 0; r < 4; r++) {
        float v = acc[i][j][r];
        if (EPI == 2) v = tanhf(v + bs);
        Cb[(size_t)(bm + wm + i * 16 + cr + r) * N + colx] = __float2bfloat16(v);
      }
    }
}

// ---------------- graph mean pooling (two stage, bf16 h_node) ----------------
__global__ void pool1_kernel(const __hip_bfloat16* __restrict__ h_node,
                             float* __restrict__ part) {
  int g = blockIdx.y, c = blockIdx.x, t = threadIdx.x;  // t over 128 dwords (256 ch)
  const unsigned* base = (const unsigned*)h_node + ((size_t)g * NPG + c * 100) * 128 + t;
  f32x2 s = (f32x2)(0.f);
  for (int i = 0; i < 100; i++) s += unpk(base[(size_t)i * 128]);
  part[(size_t)(g * 8 + c) * 256 + 2 * t] = s.x;
  part[(size_t)(g * 8 + c) * 256 + 2 * t + 1] = s.y;
}

__global__ void pool2_kernel(const float* __restrict__ part, float* __restrict__ g_pool) {
  int g = blockIdx.x, t = threadIdx.x;
  float s = 0.f;
  for (int c = 0; c < 8; c++) s += part[(size_t)(g * 8 + c) * 256 + t];
  g_pool[g * 256 + t] = s * (1.f / NPG);
}

// ---------------- build MLP input features (bf16 h_node -> bf16 feat) -------------
__global__ __launch_bounds__(256) void buildfeat_kernel(const __hip_bfloat16* __restrict__ h_node,
                                                        const float* __restrict__ g_pool,
                                                        const int* __restrict__ actions,
                                                        const float* __restrict__ tabu,
                                                        const int* __restrict__ batch,
                                                        __hip_bfloat16* __restrict__ feat) {
  int a = (blockIdx.x * blockDim.x + threadIdx.x) >> 6;
  int lane = threadIdx.x & 63;
  if (a >= NA) return;
  int n0 = actions[a * 2], n1 = actions[a * 2 + 1];
  int g = batch[n0];
  ushort4 v0 = *(const ushort4*)(h_node + (size_t)n0 * 256 + lane * 4);
  float4 vg = *(const float4*)(g_pool + (size_t)g * 256 + lane * 4);
  ushort4 v1 = *(const ushort4*)(h_node + (size_t)n1 * 256 + lane * 4);
  __hip_bfloat16* fr = feat + (size_t)a * KF;
  ushort4 ug = make_ushort4(f2b(vg.x), f2b(vg.y), f2b(vg.z), f2b(vg.w));
  *(ushort4*)(fr + lane * 4) = v0;
  *(ushort4*)(fr + 256 + lane * 4) = ug;
  *(ushort4*)(fr + 512 + lane * 4) = v1;
  *(ushort4*)(fr + 768 + lane * 4) = ug;
  if (lane < 8) {
    float t0 = (lane == 0) ? tabu[a] : 0.f;
    ushort4 u = make_ushort4(f2b(t0), 0, 0, 0);
    *(ushort4*)(fr + 1024 + lane * 4) = u;
  }
}

// ------- fused head: scores = y @ W4 + b4, then log-softmax + entropy per graph ----
__global__ __launch_bounds__(256) void head_kernel(const __hip_bfloat16* __restrict__ y,
                                                   const float* __restrict__ W4,
                                                   const float* __restrict__ b4,
                                                   float* __restrict__ out) {
  __shared__ float sc[64];
  int g = blockIdx.x;  // graph
  int t = threadIdx.x;
  int a = t >> 2, sub = t & 3;
  int aid = g * 64 + a;
  const unsigned* row = (const unsigned*)(y + (size_t)aid * 256) + sub * 32;
  const float* w = W4 + sub * 64;
  float s = 0.f;
#pragma unroll
  for (int q = 0; q < 32; q++) {
    s += bflo(row[q]) * w[2 * q] + bfhi(row[q]) * w[2 * q + 1];
  }
  s += __shfl_xor(s, 1);
  s += __shfl_xor(s, 2);
  if (sub == 0) sc[a] = s + b4[0];
  __syncthreads();
  if (t < 64) {
    float v = sc[t];
    float m = v;
    for (int off = 1; off < 64; off <<= 1) m = fmaxf(m, __shfl_xor(m, off));
    float ex = expf(v - m);
    float sum = ex;
    for (int off = 1; off < 64; off <<= 1) sum += __shfl_xor(sum, off);
    float lp = v - m - logf(sum);
    out[g * 64 + t] = lp;
    float pe = (ex / sum) * lp;
    for (int off = 1; off < 64; off <<= 1) pe += __shfl_xor(pe, off);
    if (t == 0) out[BB * APG + g] = -pe;
  }
}

extern "C" void kernel_launch(void* const* d_in, const int* in_sizes, int n_in,
                              void* d_out, int out_size, void* d_ws, size_t ws_size,
                              hipStream_t stream) {
  const float* x = (const float*)d_in[0];
  const int* ei = (const int*)d_in[1];
  const int* batch = (const int*)d_in[2];
  const int* actions = (const int*)d_in[3];
  const float* tabu = (const float*)d_in[4];
  const float* fW[3] = {(const float*)d_in[5], (const float*)d_in[9], (const float*)d_in[13]};
  const float* fas[3] = {(const float*)d_in[6], (const float*)d_in[10], (const float*)d_in[14]};
  const float* fad[3] = {(const float*)d_in[7], (const float*)d_in[11], (const float*)d_in[15]};
  const float* fb[3] = {(const float*)d_in[8], (const float*)d_in[12], (const float*)d_in[16]};
  const float* bW[3] = {(const float*)d_in[17], (const float*)d_in[21], (const float*)d_in[25]};
  const float* bas[3] = {(const float*)d_in[18], (const float*)d_in[22], (const float*)d_in[26]};
  const float* bad[3] = {(const float*)d_in[19], (const float*)d_in[23], (const float*)d_in[27]};
  const float* bb[3] = {(const float*)d_in[20], (const float*)d_in[24], (const float*)d_in[28]};
  const float* pW1 = (const float*)d_in[29];
  const float* pb1 = (const float*)d_in[30];
  const float* pW2 = (const float*)d_in[31];
  const float* pb2 = (const float*)d_in[32];
  const float* pW3 = (const float*)d_in[33];
  const float* pb3 = (const float*)d_in[34];
  const float* pW4 = (const float*)d_in[35];
  const float* pb4 = (const float*)d_in[36];
  float* out = (float*)d_out;

  char* ws = (char*)d_ws;
  size_t o = 0;
  auto alloc = [&](size_t bytes) -> void* {
    o = (o + 255) & ~(size_t)255;
    void* p = ws + o;
    o += bytes;
    return p;
  };
  int* cnt = (int*)alloc((size_t)4 * NN * 4);  // cnt[2NN] + pos[2NN]
  int* rp = (int*)alloc((size_t)(SCAN_N + 1) * 4);
  int* col = (int*)alloc(((size_t)2 * EE + 64) * 4);
  int* bsum = (int*)alloc(128 * 4);
  int* boff = (int*)alloc(128 * 4);
  float* al_s = (float*)alloc((size_t)SCAN_N * 4 * 4);  // al_s + al_d contiguous
  float* al_d = (float*)alloc((size_t)SCAN_N * 4 * 4);
  __hip_bfloat16* xp = (__hip_bfloat16*)alloc((size_t)SCAN_N * 256 * 2);    // both dirs
  __hip_bfloat16* bufA = (__hip_bfloat16*)alloc((size_t)SCAN_N * 256 * 2);  // spmm out
  __hip_bfloat16* h_node = (__hip_bfloat16*)alloc((size_t)NN * 256 * 2);
  __hip_bfloat16* wt0 = (__hip_bfloat16*)alloc((size_t)256 * KF * 2);
  __hip_bfloat16* wt1 = (__hip_bfloat16*)alloc((size_t)256 * KF * 2);
  float* part = (float*)alloc((size_t)BB * 8 * 256 * 4);
  float* g_pool = (float*)alloc((size_t)BB * 256 * 4);
  float* wa = (float*)alloc(64 * 4);
  // MLP scratch aliased onto xp (dead after last spmm)
  __hip_bfloat16* feat = xp;
  __hip_bfloat16* y1 = feat + (size_t)NA * KF;
  __hip_bfloat16* y2 = y1 + (size_t)NA * 256;

  // --- CSR build ---
  hipMemsetAsync(cnt, 0, (size_t)4 * NN * 4, stream);
  count_kernel<<<(EE + 255) / 256, 256, 0, stream>>>(ei, cnt);
  scan1_kernel<<<SCAN_N / 1024, 256, 0, stream>>>(cnt, rp, bsum);
  scan2_kernel<<<1, 128, 0, stream>>>(bsum, boff, rp);
  scan3_kernel<<<SCAN_N / 1024, 256, 0, stream>>>(rp, boff);
  fill_kernel<<<(EE + 255) / 256, 256, 0, stream>>>(ei, rp, cnt + 2 * NN, col);

  const int nwb = 3200;  // spmm blocks (32 nodes each, 4 phased iters) -- v6 proven

  // layer 1 (fin=3, H=4, C=64) both dirs: WA table + fused linear/al logits
  precomp_kernel<<<12, 256, 0, stream>>>(fW[0], bW[0], fas[0], fad[0], bas[0], bad[0], wa);
  lin1_kernel<<<1600, 256, 0, stream>>>(x, fW[0], bW[0], wa, xp, al_s, al_d);
  spmm_kernel<4, 64, 0><<<nwb, 256, 0, stream>>>(xp, al_s, al_d, rp, col,
                                                 fb[0], bb[0], bufA, 1);
  // layer 2 (256 -> H4C64) both dirs, al fused into GEMM epilogue; XCD-swizzled
  castW2_kernel<<<(2 * 256 * 256 + 255) / 256, 256, 0, stream>>>(fW[1], bW[1], wt0, wt1,
                                                                 256, 256, 256);
  gemm_mfma<1, 4, 64, 2><<<dim3(2, SCAN_N / 128), 256, 0, stream>>>(
      bufA, wt0, wt1, xp, nullptr, nullptr, fas[1], bas[1], fad[1], bad[1],
      al_s, al_d, SCAN_N, 256, 256, NN);
  spmm_kernel<4, 64, 0><<<nwb, 256, 0, stream>>>(xp, al_s, al_d, rp, col,
                                                 fb[1], bb[1], bufA, 1);
  // layer 3 (256 -> H1C128, no elu) both dirs -> h_node halves (bf16); al fused
  castW2_kernel<<<(2 * 128 * 256 + 255) / 256, 256, 0, stream>>>(fW[2], bW[2], wt0, wt1,
                                                                 256, 128, 256);
  hipMemsetAsync(al_s, 0, (size_t)2 * SCAN_N * 4, stream);  // al_s + al_d (contiguous)
  gemm_mfma<1, 1, 128, 1><<<dim3(1, SCAN_N / 128), 256, 0, stream>>>(
      bufA, wt0, wt1, xp, nullptr, nullptr, fas[2], bas[2], fad[2], bad[2],
      al_s, al_d, SCAN_N, 128, 256, NN);
  spmm_kernel<1, 128, 1><<<nwb, 256, 0, stream>>>(xp, al_s, al_d, rp, col,
                                                  fb[2], bb[2], h_node, 0);

  pool1_kernel<<<dim3(8, BB), 128, 0, stream>>>(h_node, part);
  pool2_kernel<<<BB, 256, 0, stream>>>(part, g_pool);

  // --- MLP head via MFMA ---
  buildfeat_kernel<<<NA / 4, 256, 0, stream>>>(h_node, g_pool, actions, tabu, batch, feat);
  castW1_kernel<<<(256 * KF + 255) / 256, 256, 0, stream>>>(pW1, wt0, 1025, 256, KF);
  gemm_mfma<2, 0, 64, 0><<<dim3(2, NA / 128), 256, 0, stream>>>(
      feat, wt0, wt0, y1, pb1, pb1, nullptr, nullptr, nullptr, nullptr,
      nullptr, nullptr, NA, 256, KF, 1 << 30);
  castW2_kernel<<<(2 * 256 * 256 + 255) / 256, 256, 0, stream>>>(pW2, pW3, wt0, wt1,
                                                                 256, 256, 256);
  gemm_mfma<2, 0, 64, 0><<<dim3(2, NA / 128), 256, 0, stream>>>(
      y1, wt0, wt0, y2, pb2, pb2, nullptr, nullptr, nullptr, nullptr,
      nullptr, nullptr, NA, 256, 256, 1 << 30);
  gemm_mfma<2, 0, 64, 0><<<dim3(2, NA / 128), 256, 0, stream>>>(
      y2, wt1, wt1, y1, pb3, pb3, nullptr, nullptr, nullptr, nullptr,
      nullptr, nullptr, NA, 256, 256, 1 << 30);
  head_kernel<<<BB, 256, 0, stream>>>(y1, pW4, pb4, out);
}

// Round 9
// 482.052 us; speedup vs baseline: 1.0814x; 1.0334x over previous
//
#include <hip/hip_runtime.h>
#include <hip/hip_bf16.h>
#include <math.h>

constexpr int NN  = 51200;   // total nodes
constexpr int EE  = 409600;  // edges (without self loops)
constexpr int BB  = 64;      // graphs
constexpr int APG = 64;      // actions per graph
constexpr int NPG = 800;     // nodes per graph
constexpr int SCAN_N = 2 * NN;
constexpr int NA = BB * APG; // 4096 actions
constexpr int KF = 1056;     // padded MLP input dim (1025 -> 33*32)

typedef __bf16 bf16x8 __attribute__((ext_vector_type(8)));
typedef float f32x4 __attribute__((ext_vector_type(4)));
typedef float f32x2 __attribute__((ext_vector_type(2)));
typedef __attribute__((address_space(1))) const void g_void;
typedef __attribute__((address_space(3))) void l_void;

__device__ __forceinline__ float leaky(float x) { return fmaxf(x, 0.2f * x); }
__device__ __forceinline__ float bflo(unsigned w) { return __uint_as_float(w << 16); }
__device__ __forceinline__ float bfhi(unsigned w) { return __uint_as_float(w & 0xffff0000u); }
__device__ __forceinline__ unsigned short f2b(float x) {
  __hip_bfloat16 h = __float2bfloat16(x);
  unsigned short u;
  __builtin_memcpy(&u, &h, 2);
  return u;
}
__device__ __forceinline__ unsigned pack2(float a, float b) {
  return (unsigned)f2b(a) | ((unsigned)f2b(b) << 16);
}

// ---------------- CSR scans ----------------
__global__ __launch_bounds__(256) void scan1_kernel(const int* __restrict__ cnt,
                                                    int* __restrict__ rp,
                                                    int* __restrict__ bsum) {
  __shared__ int wsum[4];
  int b = blockIdx.x, t = threadIdx.x;
  int base = b * 1024 + t * 4;
  int4 v = *(const int4*)(cnt + base);
  int s = v.x + v.y + v.z + v.w;
  int lane = t & 63, wv = t >> 6;
  int incl = s;
  for (int off = 1; off < 64; off <<= 1) {
    int u = __shfl_up(incl, off);
    if (lane >= off) incl += u;
  }
  if (lane == 63) wsum[wv] = incl;
  __syncthreads();
  int woff = 0;
  for (int i = 0; i < wv; i++) woff += wsum[i];
  int excl = woff + incl - s;
  rp[base] = excl;
  rp[base + 1] = excl + v.x;
  rp[base + 2] = excl + v.x + v.y;
  rp[base + 3] = excl + v.x + v.y + v.z;
  if (t == 255) bsum[b] = woff + incl;
}

__global__ void scan2_kernel(const int* __restrict__ bsum, int* __restrict__ boff,
                             int* __restrict__ rp) {
  __shared__ int w0;
  int t = threadIdx.x;  // 128 threads
  int v = (t < 100) ? bsum[t] : 0;
  int lane = t & 63;
  int incl = v;
  for (int off = 1; off < 64; off <<= 1) {
    int u = __shfl_up(incl, off);
    if (lane >= off) incl += u;
  }
  if (t == 63) w0 = incl;
  __syncthreads();
  int excl = incl - v + ((t >= 64) ? w0 : 0);
  if (t < 100) boff[t] = excl;
  if (t == 99) rp[SCAN_N] = excl + v;
}

__global__ __launch_bounds__(256) void scan3_kernel(int* __restrict__ rp,
                                                    const int* __restrict__ boff) {
  int b = blockIdx.x;
  int off = boff[b];
  int i = b * 1024 + threadIdx.x * 4;
  int4 v = *(int4*)(rp + i);
  v.x += off; v.y += off; v.z += off; v.w += off;
  *(int4*)(rp + i) = v;
}

__global__ void fill_kernel(const int* __restrict__ ei, const int* __restrict__ rp,
                            int* pos, int* __restrict__ col) {
  int e = blockIdx.x * blockDim.x + threadIdx.x;
  if (e >= EE) return;
  int s = ei[e], d = ei[EE + e];
  int p = atomicAdd(&pos[d], 1);
  col[rp[d] + p] = s;
  int q = atomicAdd(&pos[NN + s], 1);
  col[rp[NN + s] + q] = d;
}

// ------- WA precompute: wa[dir*24 + sd*12 + h*3 + c] = W[c]·a[h] over 64 ch -------
__global__ __launch_bounds__(256) void precomp_kernel(const float* __restrict__ Wf,
                                                      const float* __restrict__ Wb,
                                                      const float* __restrict__ asf,
                                                      const float* __restrict__ adf,
                                                      const float* __restrict__ asb,
                                                      const float* __restrict__ adb,
                                                      float* __restrict__ wa) {
  int wave = (blockIdx.x * blockDim.x + threadIdx.x) >> 6;  // 0..47
  int lane = threadIdx.x & 63;
  if (wave >= 48) return;
  int dir = wave / 24, sd = (wave / 12) % 2, h = (wave / 3) % 4, c = wave % 3;
  const float* W = dir ? Wb : Wf;
  const float* a = dir ? (sd ? adb : asb) : (sd ? adf : asf);
  float v = W[c * 256 + h * 64 + lane] * a[h * 64 + lane];
  for (int off = 1; off < 64; off <<= 1) v += __shfl_xor(v, off);
  if (lane == 0) wa[wave] = v;
}

// ------- PREAMBLE mega-kernel: count + lin1 + ALL weight casts in one launch ------
// R8 post-mortem: ~330us is spread over ~22 serial sub-54us dispatches; count
// (needs ei), lin1 (needs x,wa), and the 7 weight casts (need weights) are
// mutually independent but ran serially on one stream. Merged: blocks [0,1600)
// count, [1600,3200) lin1 (x8 iters), [3200,5536) casts -> co-scheduled, and
// casts no longer serialize between spmm/gemm later (each has its own buffer).
__global__ __launch_bounds__(256) void preamble_kernel(
    const int* __restrict__ ei, int* cnt,
    const float* __restrict__ x, const float* __restrict__ Wf,
    const float* __restrict__ Wb, const float* __restrict__ wa,
    __hip_bfloat16* __restrict__ xp, float* __restrict__ al_s,
    float* __restrict__ al_d,
    const float* __restrict__ WL2f, const float* __restrict__ WL2b,
    const float* __restrict__ WL3f, const float* __restrict__ WL3b,
    const float* __restrict__ WP1, const float* __restrict__ WP2,
    const float* __restrict__ WP3,
    __hip_bfloat16* __restrict__ wtL2f, __hip_bfloat16* __restrict__ wtL2b,
    __hip_bfloat16* __restrict__ wtL3f, __hip_bfloat16* __restrict__ wtL3b,
    __hip_bfloat16* __restrict__ wtP1, __hip_bfloat16* __restrict__ wtP2,
    __hip_bfloat16* __restrict__ wtP3) {
  int b = blockIdx.x;
  int t = threadIdx.x;
  if (b < 1600) {  // ---- count: EE = 1600*256 exactly ----
    int e = b * 256 + t;
    int s = ei[e], d = ei[EE + e];
    atomicAdd(&cnt[d], 1);
    atomicAdd(&cnt[NN + s], 1);
    return;
  }
  if (b < 3200) {  // ---- lin1: layer-1 linear + fused al logits ----
    int bb = b - 1600;
#pragma unroll 1
    for (int itq = 0; itq < 8; ++itq) {
      int idx = bb * 2048 + itq * 256 + t;  // SCAN_N*32 total
      int n = idx >> 5, grp = idx & 31;
      int dir = (n >= NN) ? 1 : 0;
      int node = dir ? n - NN : n;
      const float* W = dir ? Wb : Wf;
      int c1 = dir ? 2 : 1, c2 = dir ? 4 : 3;
      float f0 = x[node * 5], f1 = x[node * 5 + c1], f2 = x[node * 5 + c2];
      int j0 = grp * 8;
      float v[8];
#pragma unroll
      for (int j = 0; j < 8; j++)
        v[j] = f0 * W[j0 + j] + f1 * W[256 + j0 + j] + f2 * W[512 + j0 + j];
      uint4 u;
      u.x = pack2(v[0], v[1]);
      u.y = pack2(v[2], v[3]);
      u.z = pack2(v[4], v[5]);
      u.w = pack2(v[6], v[7]);
      *(uint4*)(xp + (size_t)n * 256 + j0) = u;
      if (grp < 4) {  // head = grp: 3-FMA attention logits from WA table
        const float* ws = wa + dir * 24 + grp * 3;
        const float* wd = wa + dir * 24 + 12 + grp * 3;
        al_s[n * 4 + grp] = f0 * ws[0] + f1 * ws[1] + f2 * ws[2];
        al_d[n * 4 + grp] = f0 * wd[0] + f1 * wd[1] + f2 * wd[2];
      }
    }
    return;
  }
  // ---- weight casts (transpose + K-pad), 7 jobs, 2336 blocks total ----
  int cb = b - 3200;
  const float* W;
  __hip_bfloat16* Wt;
  int K, N, Kp, rel;
  if (cb < 256)       { W = WL2f; Wt = wtL2f; K = 256;  N = 256; Kp = 256;  rel = cb; }
  else if (cb < 512)  { W = WL2b; Wt = wtL2b; K = 256;  N = 256; Kp = 256;  rel = cb - 256; }
  else if (cb < 640)  { W = WL3f; Wt = wtL3f; K = 256;  N = 128; Kp = 256;  rel = cb - 512; }
  else if (cb < 768)  { W = WL3b; Wt = wtL3b; K = 256;  N = 128; Kp = 256;  rel = cb - 640; }
  else if (cb < 1824) { W = WP1;  Wt = wtP1;  K = 1025; N = 256; Kp = 1056; rel = cb - 768; }
  else if (cb < 2080) { W = WP2;  Wt = wtP2;  K = 256;  N = 256; Kp = 256;  rel = cb - 1824; }
  else                { W = WP3;  Wt = wtP3;  K = 256;  N = 256; Kp = 256;  rel = cb - 2080; }
  int idx = rel * 256 + t;
  if (idx >= N * Kp) return;
  int n = idx / Kp, k = idx % Kp;
  Wt[idx] = (k < K) ? __float2bfloat16(W[(size_t)k * N + n]) : __float2bfloat16(0.f);
}

__device__ __forceinline__ f32x2 unpk(unsigned w) {
  f32x2 v;
  v.x = bflo(w);
  v.y = bfhi(w);
  return v;
}

// ------- SpMM v6 (session best): single-pass online-softmax, 3200 blocks ------
// col loaded once/node (cA/cB), distributed via shfl; als gather + 8 row loads
// issue together; normalization deferred to epilogue. XCD temporal phasing
// (1.6MB <= L2). Measured 53.1-53.7us/dispatch, FETCH 29.3MB.
template <int HH, int CC, int OUT_SPLIT>
__global__ __launch_bounds__(256) void spmm_kernel(const __hip_bfloat16* __restrict__ xp,
                                                   const float* __restrict__ als,
                                                   const float* __restrict__ ald,
                                                   const int* __restrict__ rp,
                                                   const int* __restrict__ col,
                                                   const float* __restrict__ biasf,
                                                   const float* __restrict__ biasb,
                                                   __hip_bfloat16* __restrict__ out_bf,
                                                   int do_elu) {
  constexpr int HC = HH * CC;    // channels per row: 256 or 128
  constexpr int RDW = HC / 2;    // dwords per row: 128 or 64
  constexpr int DL = RDW / 32;   // dwords per lane (32 lanes per node): 4 or 2
  int b = blockIdx.x;
  int xcd = b & 7;               // dispatch round-robins blocks over XCDs
  int bq = b >> 3;               // [0,400) within-XCD block index
  int dreg = xcd * 12800;        // contiguous 16-graph region per XCD
  int t = threadIdx.x;
  int wv = t >> 6, lane = t & 63;
  int sub = lane & 31, halfsel = lane >> 5;
  int lbase = lane & 32;
  int off_row = (dreg >= NN) ? NN : 0;       // uniform per block
  const float* bias = (dreg >= NN) ? biasb : biasf;
  int hch = (HH == 4) ? (sub >> 3) : 0;      // head owning this lane's channels
  int hat = (HH == 4) ? (sub & 3) : 0;       // head this lane covers in als gathers
  int eg  = (HH == 4) ? (sub >> 2) : (sub & 7);  // edge slot this lane covers
  const unsigned* xw = (const unsigned*)xp;
  float bv[2 * DL];
#pragma unroll
  for (int j = 0; j < 2 * DL; j++) bv[j] = bias[sub * 2 * DL + j];

#pragma unroll 1
  for (int it = 0; it < 4; ++it) {
    int d = dreg + it * 3200 + bq * 8 + wv * 2 + halfsel;
    int beg = rp[d];
    int deg = rp[d + 1] - beg;
    int degmax = max(deg, __shfl_xor(deg, 32));        // wave-uniform
    degmax = __builtin_amdgcn_readfirstlane(degmax);

    // node-level attention terms
    float ald_d = ald[(size_t)d * HH + hat];
    float selfw = __expf(leaky(als[(size_t)d * HH + hat] + ald_d));

    // col for edges 0..63: lane-resident (clamped; garbage-safe for deg==0)
    int e0 = (sub < deg) ? sub : (deg - 1);
    e0 = (e0 < 0) ? 0 : e0;
    int cA = col[beg + e0];
    cA = (((unsigned)cA < (unsigned)NN) ? cA : 0) + off_row;
    int cB = off_row;
    if (degmax > 32) {
      int e1 = (32 + sub < deg) ? (32 + sub) : (deg - 1);
      e1 = (e1 < 0) ? 0 : e1;
      cB = col[beg + e1];
      cB = (((unsigned)cB < (unsigned)NN) ? cB : 0) + off_row;
    }

    // self row (independent; issues early)
    unsigned swa[4] = {0u, 0u, 0u, 0u};
    {
      const unsigned* sp = xw + (size_t)d * RDW + sub * DL;
      if constexpr (DL == 4) {
        uint4 v4 = *(const uint4*)sp;
        swa[0] = v4.x; swa[1] = v4.y; swa[2] = v4.z; swa[3] = v4.w;
      } else {
        uint2 v2 = *(const uint2*)sp;
        swa[0] = v2.x; swa[1] = v2.y;
      }
    }

    f32x2 acc[DL];
#pragma unroll
    for (int j = 0; j < DL; j++) acc[j] = (f32x2)(0.f);
    float den = 0.f;

#pragma unroll
    for (int c = 0; c < 8; ++c) {  // 8-edge chunks, compile-time c
      if (c * 8 < degmax) {
        // issue: als for (edge c*8+eg, head hat) -- 32 lanes cover 8x4
        int sg = __shfl((c < 4) ? cA : cB, lbase + (c & 3) * 8 + eg);
        float alsv = als[(size_t)sg * HH + hat];
        // issue: 8 rows in flight
        uint4 w8[8];  // DL==2 uses .x/.y only
#pragma unroll
        for (int k = 0; k < 8; ++k) {
          int s = __shfl((c < 4) ? cA : cB, lbase + (c & 3) * 8 + k);
          const unsigned* p = xw + (size_t)s * RDW + sub * DL;
          if constexpr (DL == 4) {
            w8[k] = *(const uint4*)p;
          } else {
            uint2 v2 = *(const uint2*)p;
            w8[k].x = v2.x;
            w8[k].y = v2.y;
          }
        }
        // consume: unnormalized weight (exp overlaps row-load latency)
        float w = 0.f;
        if (c * 8 + eg < deg) w = __expf(leaky(alsv + ald_d));
        if constexpr (HH == 4) den += w;                 // 32 lanes = 8e x 4h
        else den += (sub < 8) ? w : 0.f;                 // mask 4x redundancy
#pragma unroll
        for (int k = 0; k < 8; ++k) {  // padded slots: w==0 contributes 0
          float a = __shfl(w, lbase + ((HH == 4) ? (k * 4 + hch) : k));
          acc[0] += a * unpk(w8[k].x);
          acc[1] += a * unpk(w8[k].y);
          if constexpr (DL == 4) {
            acc[2] += a * unpk(w8[k].z);
            acc[3] += a * unpk(w8[k].w);
          }
        }
      }
    }
    for (int e = 64; e < degmax; ++e) {  // deg>64 fallback (practically never)
      if (e < deg) {
        int s = col[beg + e];
        s = (((unsigned)s < (unsigned)NN) ? s : 0) + off_row;
        float w = __expf(leaky(als[(size_t)s * HH + hat] + ald_d));
        if constexpr (HH == 4) den += (sub < 4) ? w : 0.f;
        else den += (sub == 0) ? w : 0.f;
        float a;
        if constexpr (HH == 4) a = __shfl(w, lbase + hch);
        else a = w;
        const unsigned* p = xw + (size_t)s * RDW + sub * DL;
        acc[0] += a * unpk(p[0]);
        acc[1] += a * unpk(p[1]);
        if constexpr (DL == 4) {
          acc[2] += a * unpk(p[2]);
          acc[3] += a * unpk(p[3]);
        }
      }
    }

    // reduce den per head, normalize once at the end
    if constexpr (HH == 4) {
      den += __shfl_xor(den, 4);
      den += __shfl_xor(den, 8);
      den += __shfl_xor(den, 16);
    } else {
      den += __shfl_xor(den, 1);
      den += __shfl_xor(den, 2);
      den += __shfl_xor(den, 4);
      den += __shfl_xor(den, 8);
      den += __shfl_xor(den, 16);
    }
    float inv = 1.f / (den + selfw + 1e-16f);
    float invc = inv, selfc = selfw;
    if constexpr (HH == 4) {  // broadcast head hch's values to channel lanes
      invc = __shfl(inv, lbase + hch);
      selfc = __shfl(selfw, lbase + hch);
    }

    float v[2 * DL];
#pragma unroll
    for (int j = 0; j < DL; j++) {
      f32x2 r = acc[j] + selfc * unpk(swa[j]);
      v[2 * j] = r.x * invc + bv[2 * j];
      v[2 * j + 1] = r.y * invc + bv[2 * j + 1];
    }
    if (do_elu) {
#pragma unroll
      for (int j = 0; j < 2 * DL; j++) v[j] = v[j] > 0.f ? v[j] : (__expf(v[j]) - 1.f);
    }
    if constexpr (OUT_SPLIT) {  // layer3: DL==2, write h_node half-row
      int nd = (d < NN) ? d : d - NN;
      int oo = (d < NN) ? 0 : 64;  // dword offset (128 bf16)
      uint2 u;
      u.x = pack2(v[0], v[1]);
      u.y = pack2(v[2], v[3]);
      *(uint2*)((unsigned*)out_bf + (size_t)nd * 128 + oo + sub * 2) = u;
    } else {
      uint4 u;
      u.x = pack2(v[0], v[1]);
      u.y = pack2(v[2], v[3]);
      u.z = pack2(v[4], v[5]);
      u.w = pack2(v[6], v[7]);
      *(uint4*)((unsigned*)out_bf + (size_t)d * RDW + sub * DL) = u;
    }
  }
}

// ---------------- bf16 MFMA GEMM: C[M,N] = A[M,K] @ Bt[N,K]^T ----------------
// R5 form (plain block mapping; R8 A/B showed XCD swizzle = null here).
template <int EPI, int ALH, int ALCC>
__global__ __launch_bounds__(256) void gemm_mfma(const __hip_bfloat16* __restrict__ A,
                                                 const __hip_bfloat16* __restrict__ Bt0,
                                                 const __hip_bfloat16* __restrict__ Bt1,
                                                 __hip_bfloat16* __restrict__ Cb,
                                                 const float* __restrict__ bias0,
                                                 const float* __restrict__ bias1,
                                                 const float* __restrict__ asv0,
                                                 const float* __restrict__ asv1,
                                                 const float* __restrict__ adv0,
                                                 const float* __restrict__ adv1,
                                                 float* __restrict__ al_s,
                                                 float* __restrict__ al_d,
                                                 int M, int N, int K, int Mhalf) {
  __shared__ __align__(16) __hip_bfloat16 As[128 * 32];
  __shared__ __align__(16) __hip_bfloat16 Bs[128 * 32];
  int t = threadIdx.x;
  int wave = t >> 6, lane = t & 63;
  int wm = (wave >> 1) * 64, wn = (wave & 1) * 64;
  int bm = blockIdx.y * 128, bn = blockIdx.x * 128;
  bool second = bm >= Mhalf;
  const __hip_bfloat16* Bt = second ? Bt1 : Bt0;
  const float* bias = second ? bias1 : bias0;
  const float* asv = second ? asv1 : asv0;
  const float* adv = second ? adv1 : adv0;

  int r0 = t >> 2, c0 = (t & 3) * 8;
  const __hip_bfloat16* Ag0 = A + (size_t)(bm + r0) * K + c0;
  const __hip_bfloat16* Ag1 = A + (size_t)(bm + r0 + 64) * K + c0;
  const __hip_bfloat16* Bg0 = Bt + (size_t)(bn + r0) * K + c0;
  const __hip_bfloat16* Bg1 = Bt + (size_t)(bn + r0 + 64) * K + c0;
  __hip_bfloat16* Asp0 = As + t * 8;
  __hip_bfloat16* Asp1 = As + 64 * 8 * 4 + t * 8;
  __hip_bfloat16* Bsp0 = Bs + t * 8;
  __hip_bfloat16* Bsp1 = Bs + 64 * 8 * 4 + t * 8;

  f32x4 acc[4][4];
#pragma unroll
  for (int i = 0; i < 4; i++)
#pragma unroll
    for (int j = 0; j < 4; j++) acc[i][j] = (f32x4)(0.f);

  int frag_off = (lane & 15) * 32 + (lane >> 4) * 8;
  const __hip_bfloat16* Ab = As + wm * 32 + frag_off;
  const __hip_bfloat16* Bb = Bs + wn * 32 + frag_off;

  for (int k0 = 0; k0 < K; k0 += 32) {
    __syncthreads();
    __builtin_amdgcn_global_load_lds((g_void*)(Ag0 + k0), (l_void*)Asp0, 16, 0, 0);
    __builtin_amdgcn_global_load_lds((g_void*)(Ag1 + k0), (l_void*)Asp1, 16, 0, 0);
    __builtin_amdgcn_global_load_lds((g_void*)(Bg0 + k0), (l_void*)Bsp0, 16, 0, 0);
    __builtin_amdgcn_global_load_lds((g_void*)(Bg1 + k0), (l_void*)Bsp1, 16, 0, 0);
    __syncthreads();
    bf16x8 af[4], bfr[4];
#pragma unroll
    for (int i = 0; i < 4; i++) af[i] = *(const bf16x8*)(Ab + i * 16 * 32);
#pragma unroll
    for (int j = 0; j < 4; j++) bfr[j] = *(const bf16x8*)(Bb + j * 16 * 32);
#pragma unroll
    for (int i = 0; i < 4; i++)
#pragma unroll
      for (int j = 0; j < 4; j++)
        acc[i][j] = __builtin_amdgcn_mfma_f32_16x16x32_bf16(af[i], bfr[j], acc[i][j], 0, 0, 0);
  }

  int cr = (lane >> 4) * 4, cc = lane & 15;

  if constexpr (ALH > 0) {
    int head = (bn + wn) / ALCC;
    float as_c[4], ad_c[4];
#pragma unroll
    for (int j = 0; j < 4; j++) {
      int colx = bn + wn + j * 16 + cc;
      as_c[j] = asv[colx];
      ad_c[j] = adv[colx];
    }
#pragma unroll
    for (int i = 0; i < 4; i++)
#pragma unroll
      for (int r = 0; r < 4; r++) {
        float ps = 0.f, pd = 0.f;
#pragma unroll
        for (int j = 0; j < 4; j++) {
          ps += acc[i][j][r] * as_c[j];
          pd += acc[i][j][r] * ad_c[j];
        }
        ps += __shfl_xor(ps, 1); pd += __shfl_xor(pd, 1);
        ps += __shfl_xor(ps, 2); pd += __shfl_xor(pd, 2);
        ps += __shfl_xor(ps, 4); pd += __shfl_xor(pd, 4);
        ps += __shfl_xor(ps, 8); pd += __shfl_xor(pd, 8);
        if ((lane & 15) == 0) {
          int row = bm + wm + i * 16 + cr + r;
          if (ALCC > 64) {
            atomicAdd(&al_s[row * ALH + head], ps);
            atomicAdd(&al_d[row * ALH + head], pd);
          } else {
            al_s[row * ALH + head] = ps;
            al_d[row * ALH + head] = pd;
          }
        }
      }
  }

#pragma unroll
  for (int i = 0; i < 4; i++)
#pragma unroll
    for (int j = 0; j < 4; j++) {
      int colx = bn + wn + j * 16 + cc;
      float bs = (EPI == 2) ? bias[colx] : 0.f;
#pragma unroll
      for (int r = 0; r < 4; r++) {
        float v = acc[i][j][r];
        if (EPI == 2) v = tanhf(v + bs);
        Cb[(size_t)(bm + wm + i * 16 + cr + r) * N + colx] = __float2bfloat16(v);
      }
    }
}

// ---------------- graph mean pooling (two stage, bf16 h_node) ----------------
__global__ void pool1_kernel(const __hip_bfloat16* __restrict__ h_node,
                             float* __restrict__ part) {
  int g = blockIdx.y, c = blockIdx.x, t = threadIdx.x;  // t over 128 dwords (256 ch)
  const unsigned* base = (const unsigned*)h_node + ((size_t)g * NPG + c * 100) * 128 + t;
  f32x2 s = (f32x2)(0.f);
  for (int i = 0; i < 100; i++) s += unpk(base[(size_t)i * 128]);
  part[(size_t)(g * 8 + c) * 256 + 2 * t] = s.x;
  part[(size_t)(g * 8 + c) * 256 + 2 * t + 1] = s.y;
}

__global__ void pool2_kernel(const float* __restrict__ part, float* __restrict__ g_pool) {
  int g = blockIdx.x, t = threadIdx.x;
  float s = 0.f;
  for (int c = 0; c < 8; c++) s += part[(size_t)(g * 8 + c) * 256 + t];
  g_pool[g * 256 + t] = s * (1.f / NPG);
}

// ---------------- build MLP input features (bf16 h_node -> bf16 feat) -------------
__global__ __launch_bounds__(256) void buildfeat_kernel(const __hip_bfloat16* __restrict__ h_node,
                                                        const float* __restrict__ g_pool,
                                                        const int* __restrict__ actions,
                                                        const float* __restrict__ tabu,
                                                        const int* __restrict__ batch,
                                                        __hip_bfloat16* __restrict__ feat) {
  int a = (blockIdx.x * blockDim.x + threadIdx.x) >> 6;
  int lane = threadIdx.x & 63;
  if (a >= NA) return;
  int n0 = actions[a * 2], n1 = actions[a * 2 + 1];
  int g = batch[n0];
  ushort4 v0 = *(const ushort4*)(h_node + (size_t)n0 * 256 + lane * 4);
  float4 vg = *(const float4*)(g_pool + (size_t)g * 256 + lane * 4);
  ushort4 v1 = *(const ushort4*)(h_node + (size_t)n1 * 256 + lane * 4);
  __hip_bfloat16* fr = feat + (size_t)a * KF;
  ushort4 ug = make_ushort4(f2b(vg.x), f2b(vg.y), f2b(vg.z), f2b(vg.w));
  *(ushort4*)(fr + lane * 4) = v0;
  *(ushort4*)(fr + 256 + lane * 4) = ug;
  *(ushort4*)(fr + 512 + lane * 4) = v1;
  *(ushort4*)(fr + 768 + lane * 4) = ug;
  if (lane < 8) {
    float t0 = (lane == 0) ? tabu[a] : 0.f;
    ushort4 u = make_ushort4(f2b(t0), 0, 0, 0);
    *(ushort4*)(fr + 1024 + lane * 4) = u;
  }
}

// ------- fused head: scores = y @ W4 + b4, then log-softmax + entropy per graph ----
__global__ __launch_bounds__(256) void head_kernel(const __hip_bfloat16* __restrict__ y,
                                                   const float* __restrict__ W4,
                                                   const float* __restrict__ b4,
                                                   float* __restrict__ out) {
  __shared__ float sc[64];
  int g = blockIdx.x;  // graph
  int t = threadIdx.x;
  int a = t >> 2, sub = t & 3;
  int aid = g * 64 + a;
  const unsigned* row = (const unsigned*)(y + (size_t)aid * 256) + sub * 32;
  const float* w = W4 + sub * 64;
  float s = 0.f;
#pragma unroll
  for (int q = 0; q < 32; q++) {
    s += bflo(row[q]) * w[2 * q] + bfhi(row[q]) * w[2 * q + 1];
  }
  s += __shfl_xor(s, 1);
  s += __shfl_xor(s, 2);
  if (sub == 0) sc[a] = s + b4[0];
  __syncthreads();
  if (t < 64) {
    float v = sc[t];
    float m = v;
    for (int off = 1; off < 64; off <<= 1) m = fmaxf(m, __shfl_xor(m, off));
    float ex = expf(v - m);
    float sum = ex;
    for (int off = 1; off < 64; off <<= 1) sum += __shfl_xor(sum, off);
    float lp = v - m - logf(sum);
    out[g * 64 + t] = lp;
    float pe = (ex / sum) * lp;
    for (int off = 1; off < 64; off <<= 1) pe += __shfl_xor(pe, off);
    if (t == 0) out[BB * APG + g] = -pe;
  }
}

extern "C" void kernel_launch(void* const* d_in, const int* in_sizes, int n_in,
                              void* d_out, int out_size, void* d_ws, size_t ws_size,
                              hipStream_t stream) {
  const float* x = (const float*)d_in[0];
  const int* ei = (const int*)d_in[1];
  const int* batch = (const int*)d_in[2];
  const int* actions = (const int*)d_in[3];
  const float* tabu = (const float*)d_in[4];
  const float* fW[3] = {(const float*)d_in[5], (const float*)d_in[9], (const float*)d_in[13]};
  const float* fas[3] = {(const float*)d_in[6], (const float*)d_in[10], (const float*)d_in[14]};
  const float* fad[3] = {(const float*)d_in[7], (const float*)d_in[11], (const float*)d_in[15]};
  const float* fb[3] = {(const float*)d_in[8], (const float*)d_in[12], (const float*)d_in[16]};
  const float* bW[3] = {(const float*)d_in[17], (const float*)d_in[21], (const float*)d_in[25]};
  const float* bas[3] = {(const float*)d_in[18], (const float*)d_in[22], (const float*)d_in[26]};
  const float* bad[3] = {(const float*)d_in[19], (const float*)d_in[23], (const float*)d_in[27]};
  const float* bb[3] = {(const float*)d_in[20], (const float*)d_in[24], (const float*)d_in[28]};
  const float* pW1 = (const float*)d_in[29];
  const float* pb1 = (const float*)d_in[30];
  const float* pW2 = (const float*)d_in[31];
  const float* pb2 = (const float*)d_in[32];
  const float* pW3 = (const float*)d_in[33];
  const float* pb3 = (const float*)d_in[34];
  const float* pW4 = (const float*)d_in[35];
  const float* pb4 = (const float*)d_in[36];
  float* out = (float*)d_out;

  char* ws = (char*)d_ws;
  size_t o = 0;
  auto alloc = [&](size_t bytes) -> void* {
    o = (o + 255) & ~(size_t)255;
    void* p = ws + o;
    o += bytes;
    return p;
  };
  int* cnt = (int*)alloc((size_t)4 * NN * 4);  // cnt[2NN] + pos[2NN]
  int* rp = (int*)alloc((size_t)(SCAN_N + 1) * 4);
  int* col = (int*)alloc(((size_t)2 * EE + 64) * 4);
  int* bsum = (int*)alloc(128 * 4);
  int* boff = (int*)alloc(128 * 4);
  float* al_s = (float*)alloc((size_t)SCAN_N * 4 * 4);  // al_s then al_d (contiguous allocs)
  float* al_d = (float*)alloc((size_t)SCAN_N * 4 * 4);
  __hip_bfloat16* xp = (__hip_bfloat16*)alloc((size_t)SCAN_N * 256 * 2);    // both dirs
  __hip_bfloat16* bufA = (__hip_bfloat16*)alloc((size_t)SCAN_N * 256 * 2);  // spmm out
  __hip_bfloat16* h_node = (__hip_bfloat16*)alloc((size_t)NN * 256 * 2);
  __hip_bfloat16* wtL2f = (__hip_bfloat16*)alloc((size_t)256 * 256 * 2);
  __hip_bfloat16* wtL2b = (__hip_bfloat16*)alloc((size_t)256 * 256 * 2);
  __hip_bfloat16* wtL3f = (__hip_bfloat16*)alloc((size_t)128 * 256 * 2);
  __hip_bfloat16* wtL3b = (__hip_bfloat16*)alloc((size_t)128 * 256 * 2);
  __hip_bfloat16* wtP1  = (__hip_bfloat16*)alloc((size_t)256 * KF * 2);
  __hip_bfloat16* wtP2  = (__hip_bfloat16*)alloc((size_t)256 * 256 * 2);
  __hip_bfloat16* wtP3  = (__hip_bfloat16*)alloc((size_t)256 * 256 * 2);
  float* part = (float*)alloc((size_t)BB * 8 * 256 * 4);
  float* g_pool = (float*)alloc((size_t)BB * 256 * 4);
  float* wa = (float*)alloc(64 * 4);
  // MLP scratch aliased onto xp (dead after last spmm)
  __hip_bfloat16* feat = xp;
  __hip_bfloat16* y1 = feat + (size_t)NA * KF;
  __hip_bfloat16* y2 = y1 + (size_t)NA * 256;

  // --- preamble: memset + precomp, then count ∥ lin1 ∥ all weight casts ---
  hipMemsetAsync(cnt, 0, (size_t)4 * NN * 4, stream);
  precomp_kernel<<<12, 256, 0, stream>>>(fW[0], bW[0], fas[0], fad[0], bas[0], bad[0], wa);
  preamble_kernel<<<5536, 256, 0, stream>>>(
      ei, cnt, x, fW[0], bW[0], wa, xp, al_s, al_d,
      fW[1], bW[1], fW[2], bW[2], pW1, pW2, pW3,
      wtL2f, wtL2b, wtL3f, wtL3b, wtP1, wtP2, wtP3);
  // --- CSR build (scan chain + fill) ---
  scan1_kernel<<<SCAN_N / 1024, 256, 0, stream>>>(cnt, rp, bsum);
  scan2_kernel<<<1, 128, 0, stream>>>(bsum, boff, rp);
  scan3_kernel<<<SCAN_N / 1024, 256, 0, stream>>>(rp, boff);
  fill_kernel<<<(EE + 255) / 256, 256, 0, stream>>>(ei, rp, cnt + 2 * NN, col);

  const int nwb = 3200;  // spmm blocks (32 nodes each, 4 phased iters) -- v6 proven

  // layer 1 aggregation
  spmm_kernel<4, 64, 0><<<nwb, 256, 0, stream>>>(xp, al_s, al_d, rp, col,
                                                 fb[0], bb[0], bufA, 1);
  // layer 2 (256 -> H4C64) both dirs, al fused into GEMM epilogue
  gemm_mfma<1, 4, 64><<<dim3(2, SCAN_N / 128), 256, 0, stream>>>(
      bufA, wtL2f, wtL2b, xp, nullptr, nullptr, fas[1], bas[1], fad[1], bad[1],
      al_s, al_d, SCAN_N, 256, 256, NN);
  spmm_kernel<4, 64, 0><<<nwb, 256, 0, stream>>>(xp, al_s, al_d, rp, col,
                                                 fb[1], bb[1], bufA, 1);
  // layer 3 (256 -> H1C128, no elu) both dirs -> h_node halves (bf16); al fused
  // zero the FULL al_s and al_d[0..SCAN_N) span (atomicAdd accumulates onto it)
  hipMemsetAsync(al_s, 0, (size_t)8 * SCAN_N * 4, stream);
  gemm_mfma<1, 1, 128><<<dim3(1, SCAN_N / 128), 256, 0, stream>>>(
      bufA, wtL3f, wtL3b, xp, nullptr, nullptr, fas[2], bas[2], fad[2], bad[2],
      al_s, al_d, SCAN_N, 128, 256, NN);
  spmm_kernel<1, 128, 1><<<nwb, 256, 0, stream>>>(xp, al_s, al_d, rp, col,
                                                  fb[2], bb[2], h_node, 0);

  pool1_kernel<<<dim3(8, BB), 128, 0, stream>>>(h_node, part);
  pool2_kernel<<<BB, 256, 0, stream>>>(part, g_pool);

  // --- MLP head via MFMA (weights pre-cast in preamble) ---
  buildfeat_kernel<<<NA / 4, 256, 0, stream>>>(h_node, g_pool, actions, tabu, batch, feat);
  gemm_mfma<2, 0, 64><<<dim3(2, NA / 128), 256, 0, stream>>>(
      feat, wtP1, wtP1, y1, pb1, pb1, nullptr, nullptr, nullptr, nullptr,
      nullptr, nullptr, NA, 256, KF, 1 << 30);
  gemm_mfma<2, 0, 64><<<dim3(2, NA / 128), 256, 0, stream>>>(
      y1, wtP2, wtP2, y2, pb2, pb2, nullptr, nullptr, nullptr, nullptr,
      nullptr, nullptr, NA, 256, 256, 1 << 30);
  gemm_mfma<2, 0, 64><<<dim3(2, NA / 128), 256, 0, stream>>>(
      y2, wtP3, wtP3, y1, pb3, pb3, nullptr, nullptr, nullptr, nullptr,
      nullptr, nullptr, NA, 256, 256, 1 << 30);
  head_kernel<<<BB, 256, 0, stream>>>(y1, pW4, pb4, out);
}